// Round 10
// baseline (973.332 us; speedup 1.0000x reference)
//
#include <hip/hip_runtime.h>
#include <math.h>

#define N_NODES_C 50000
#define N_GRAPHS_C 64
#define HDIM 128

typedef short bf16x8 __attribute__((ext_vector_type(8)));
typedef short shortx4 __attribute__((ext_vector_type(4)));
typedef float floatx4 __attribute__((ext_vector_type(4)));
typedef _Float16 halfx8 __attribute__((ext_vector_type(8)));

// split f32 -> hi (truncated bf16) + lo (bf16 of exact residual)
__device__ __forceinline__ void cvt_pair(float x, short& h, short& l) {
    union { float f; unsigned u; } a; a.f = x;
    h = (short)(a.u >> 16);
    union { unsigned u; float f; } b; b.u = a.u & 0xFFFF0000u;
    union { float f; unsigned u; } c; c.f = x - b.f;   // exact residual
    l = (short)(c.u >> 16);
}

__device__ __forceinline__ float b2f(short s) {
    union { unsigned u; float f; } x; x.u = ((unsigned)(unsigned short)s) << 16;
    return x.f;
}

// async global->LDS copy, 16 B per lane, LDS dest = wave-uniform base + lane*16
__device__ __forceinline__ void gld_lds16(const void* gsrc, void* ldst) {
    __builtin_amdgcn_global_load_lds(
        (const __attribute__((address_space(1))) unsigned int*)gsrc,
        (__attribute__((address_space(3))) unsigned int*)ldst,
        16, 0, 0);
}

// ============ MFMA GEMM with global_load_lds staging ============
// R6 config FROZEN: AF32=1 dbuf 64KB (256,2); AF32=0 single 32KB (256,3);
// bf16 granule XOR-swizzle both sides; XCD-bijective block swizzle.
// mode 0 writes MIXED output: cols [0,128) -> f32 Q buffer (ld 128),
// cols [128,640) -> fp16 KV buffer (ld 512). B layout unchanged.
// mode 2: planes = relu(v + bias)  (ldc = 128)
// mode 3: planes = relu(gate*v+bias' + (1-gate)*prev)  (ldc = 128)
#define GBM 128
#define GBN 128
#define GBK 32

template<int AF32>
__global__ __launch_bounds__(256, AF32 ? 2 : 3) void gemm_planes(
    const void* __restrict__ Aptr, const short* __restrict__ Alo, int lda,
    const short* __restrict__ Bhi, const short* __restrict__ Blo, int ldbt,
    const float* __restrict__ bias,
    float* __restrict__ Cf, short* __restrict__ Chi, short* __restrict__ Clo,
    int M, int Ntot, int K,
    int mode, const float* __restrict__ skipGate,
    const short* __restrict__ Phi, const short* __restrict__ Plo)
{
    constexpr int ASZ = AF32 ? (GBM * GBK * 2) : (GBM * GBK);  // shorts / buffer
    constexpr int BSZ = GBN * GBK;
    constexpr int NB  = AF32 ? 2 : 1;                          // LDS buffers
    __shared__ __align__(16) short AsH[NB * ASZ];
    __shared__ __align__(16) short AsL[AF32 ? 8 : ASZ];
    __shared__ __align__(16) short BsH[NB * BSZ];
    __shared__ __align__(16) short BsL[NB * BSZ];

    const int t = threadIdx.x;
    const int lane = t & 63;
    const int wave = t >> 6;
    const int wm = wave & 1, wn = wave >> 1;
    const int quad = lane >> 4, l15 = lane & 15;

    // XCD-bijective chunked swizzle (valid for any nwg), column-fastest decode
    const int nwg = gridDim.x, bid0 = blockIdx.x;
    const int qq = nwg >> 3, rr = nwg & 7;
    const int xcd = bid0 & 7, idx = bid0 >> 3;
    const int swz = (xcd < rr ? xcd * (qq + 1)
                              : rr * (qq + 1) + (xcd - rr) * qq) + idx;
    const int ncb = (Ntot + GBN - 1) / GBN;
    const long row0 = (long)(swz / ncb) * GBM;
    const long col0 = (long)(swz % ncb) * GBN;

    floatx4 acc[4][4];
    #pragma unroll
    for (int i = 0; i < 4; ++i)
        #pragma unroll
        for (int j = 0; j < 4; ++j)
            acc[i][j] = (floatx4){0.f, 0.f, 0.f, 0.f};

    const int nkt = K / GBK;

    auto stage = [&](int buf, int k0) {
        if constexpr (AF32) {
            const float* Af = (const float*)Aptr;
            int r8 = lane >> 3, kc8 = lane & 7;
            #pragma unroll
            for (int cc = 0; cc < 4; ++cc) {
                int ch = wave * 4 + cc;
                long gr = row0 + ch * 8 + r8;
                if (gr > M - 1) gr = M - 1;
                gld_lds16(Af + gr * lda + k0 + ((kc8 ^ r8) << 2),
                          AsH + buf * ASZ + ch * 512);
            }
        } else {
            const short* Ahi = (const short*)Aptr;
            int r16 = lane >> 2, g4 = lane & 3;
            int gs = (g4 ^ ((r16 >> 1) & 3)) * 8;   // granule swizzle (src side)
            #pragma unroll
            for (int cc = 0; cc < 2; ++cc) {
                int ch = wave * 2 + cc;
                long gr = row0 + ch * 16 + r16;
                if (gr > M - 1) gr = M - 1;
                long go = gr * lda + k0 + gs;
                gld_lds16(Ahi + go, AsH + ch * 512);
                gld_lds16(Alo + go, AsL + ch * 512);
            }
        }
        {
            int r16 = lane >> 2, g4 = lane & 3;
            int gs = (g4 ^ ((r16 >> 1) & 3)) * 8;   // granule swizzle (src side)
            #pragma unroll
            for (int cc = 0; cc < 2; ++cc) {
                int ch = wave * 2 + cc;
                long gc = col0 + ch * 16 + r16;
                if (gc > Ntot - 1) gc = Ntot - 1;
                long go = gc * ldbt + k0 + gs;
                gld_lds16(Bhi + go, BsH + buf * BSZ + ch * 512);
                gld_lds16(Blo + go, BsL + buf * BSZ + ch * 512);
            }
        }
    };

    auto compute = [&](int buf) {
        bf16x8 aH[4], aL[4], bH[4], bL[4];
        if constexpr (AF32) {
            #pragma unroll
            for (int i = 0; i < 4; ++i) {
                int row = wm * 64 + i * 16 + l15;
                const float* fr = (const float*)(AsH + buf * ASZ) + row * 32;
                int x7 = row & 7;
                float4 f0 = *(const float4*)(fr + (((quad * 2)     ^ x7) << 2));
                float4 f1 = *(const float4*)(fr + (((quad * 2 + 1) ^ x7) << 2));
                short h0,h1,h2,h3,h4,h5,h6,h7, l0,l1,l2,l3,l4,l5,l6,l7;
                cvt_pair(f0.x,h0,l0); cvt_pair(f0.y,h1,l1);
                cvt_pair(f0.z,h2,l2); cvt_pair(f0.w,h3,l3);
                cvt_pair(f1.x,h4,l4); cvt_pair(f1.y,h5,l5);
                cvt_pair(f1.z,h6,l6); cvt_pair(f1.w,h7,l7);
                aH[i] = (bf16x8){h0,h1,h2,h3,h4,h5,h6,h7};
                aL[i] = (bf16x8){l0,l1,l2,l3,l4,l5,l6,l7};
            }
        } else {
            #pragma unroll
            for (int i = 0; i < 4; ++i) {
                int row = wm * 64 + i * 16 + l15;
                int off = row * 32 + ((quad ^ ((row >> 1) & 3)) * 8);
                aH[i] = *(const bf16x8*)&AsH[off];
                aL[i] = *(const bf16x8*)&AsL[off];
            }
        }
        #pragma unroll
        for (int j = 0; j < 4; ++j) {
            int row = wn * 64 + j * 16 + l15;
            int off = buf * BSZ + row * 32 + ((quad ^ ((row >> 1) & 3)) * 8);
            bH[j] = *(const bf16x8*)&BsH[off];
            bL[j] = *(const bf16x8*)&BsL[off];
        }
        #pragma unroll
        for (int i = 0; i < 4; ++i)
            #pragma unroll
            for (int j = 0; j < 4; ++j) {
                acc[i][j] = __builtin_amdgcn_mfma_f32_16x16x32_bf16(aH[i], bH[j], acc[i][j], 0, 0, 0);
                acc[i][j] = __builtin_amdgcn_mfma_f32_16x16x32_bf16(aH[i], bL[j], acc[i][j], 0, 0, 0);
                acc[i][j] = __builtin_amdgcn_mfma_f32_16x16x32_bf16(aL[i], bH[j], acc[i][j], 0, 0, 0);
            }
    };

    if constexpr (AF32) {
        stage(0, 0);
        int cur = 0;
        for (int kt = 0; kt < nkt; ++kt) {
            __syncthreads();
            if (kt + 1 < nkt) stage(cur ^ 1, (kt + 1) * GBK);
            compute(cur);
            cur ^= 1;
        }
    } else {
        for (int kt = 0; kt < nkt; ++kt) {
            stage(0, kt * GBK);
            __syncthreads();
            compute(0);
            __syncthreads();
        }
    }

    float gate = 0.f;
    if (mode == 3) gate = 1.f / (1.f + __expf(-skipGate[0]));
    _Float16* kvout = (_Float16*)Chi;   // mode 0 fp16 KV destination

    #pragma unroll
    for (int i = 0; i < 4; ++i) {
        #pragma unroll
        for (int r4 = 0; r4 < 4; ++r4) {
            long grow = row0 + wm * 64 + i * 16 + quad * 4 + r4;
            if (grow >= M) continue;
            #pragma unroll
            for (int j = 0; j < 4; ++j) {
                long gcol = col0 + wn * 64 + j * 16 + l15;
                if (gcol >= Ntot) continue;
                float v = acc[i][j][r4];
                if (bias) v += bias[gcol];
                if (mode == 0) {
                    if (gcol < 128) Cf[grow * 128 + gcol] = v;
                    else kvout[grow * 512 + (gcol - 128)] = (_Float16)v;
                } else {
                    if (mode == 3) {
                        long po = grow * 128 + gcol;
                        float pv = b2f(Phi[po]) + b2f(Plo[po]);
                        v = gate * v + (1.f - gate) * pv;
                    }
                    v = fmaxf(v, 0.f);
                    short hh, ll; cvt_pair(v, hh, ll);
                    Chi[grow * 128 + gcol] = hh;
                    Clo[grow * 128 + gcol] = ll;
                }
            }
        }
    }
}

// ============ build fused WbigT[640, F] planes + bias640 + WaT transpose ============
// Column layout: [0,128) q | per (relation r, head h) contiguous 128-col
// block: k_rh (64) then v_rh (64). Block order: r0h0, r0h1, r1h0, r1h1.
// blockIdx.y in [640,768) writes the WaT transpose planes (fused).
__global__ __launch_bounds__(256) void build_wbigT_p(
    const float* __restrict__ Wq, const float* __restrict__ bq,
    const float* __restrict__ Wk, const float* __restrict__ bk,
    const float* __restrict__ Wv, const float* __restrict__ bv,
    const float* __restrict__ arel, const float* __restrict__ mrel,
    const float* __restrict__ Wa,
    short* __restrict__ WThi, short* __restrict__ WTlo,
    short* __restrict__ WaThi, short* __restrict__ WaTlo,
    float* __restrict__ bias, int F)
{
    __shared__ float Trow[64];
    int c = blockIdx.y;
    int f = blockIdx.x * 256 + threadIdx.x;

    if (c >= 640) {                       // fused Wa transpose
        int cc = c - 640;                 // 0..127
        if (blockIdx.x == 0 && threadIdx.x < 128) {
            int ff = threadIdx.x;
            short hh, ll; cvt_pair(Wa[(long)ff * 128 + cc], hh, ll);
            WaThi[cc * 128 + ff] = hh;
            WaTlo[cc * 128 + ff] = ll;
        }
        return;
    }

    float w = 0.f, b = 0.f;
    if (c < 128) {
        if (f < F) w = Wq[(long)f * 128 + c];
        b = bq[c];
    } else {
        int cc = c - 128;              // 0..511
        int r  = cc >> 8;              // relation
        int hb = cc & 255;             // within relation
        int h  = hb >> 7;              // head
        int kv = (hb >> 6) & 1;        // 0 = k, 1 = v
        int e  = hb & 63;              // element within head
        const float* Wsrc = kv ? Wv : Wk;
        const float* bsrc = kv ? bv : bk;
        const float* T    = kv ? mrel : arel;
        const float* Tr = T + (long)(r * 2 + h) * 4096 + e;
        if (threadIdx.x < 64) Trow[threadIdx.x] = Tr[(long)threadIdx.x * 64];
        __syncthreads();
        if (f < F) {
            const float* Wrow = Wsrc + (long)f * 128 + h * 64;
            float s = 0.f;
            #pragma unroll 4
            for (int d = 0; d < 64; ++d) s = fmaf(Wrow[d], Trow[d], s);
            w = s;
        }
        if (f == 0) {
            const float* brow = bsrc + h * 64;
            float sb = 0.f;
            for (int d = 0; d < 64; ++d) sb = fmaf(brow[d], Trow[d], sb);
            b = sb;
        }
    }
    if (f < F) {
        short hh, ll; cvt_pair(w, hh, ll);
        WThi[(long)c * F + f] = hh;
        WTlo[(long)c * F + f] = ll;
    }
    if (f == 0) bias[c] = b;
}

// ============ CSR build, both relations per launch (blockIdx.y = r) ============
__global__ void csr_count2(const int* __restrict__ e0p, const int* __restrict__ e1p,
                           int* __restrict__ counts, int E, int N)
{
    int e = blockIdx.x * 256 + threadIdx.x;
    int r = blockIdx.y;
    const int* dst = (r ? e1p : e0p) + E;
    if (e < E) atomicAdd(&counts[r * N + dst[e]], 1);
}

__global__ __launch_bounds__(1024) void csr_scan2(
    const int* __restrict__ counts,
    int* __restrict__ off0, int* __restrict__ off1,
    int* __restrict__ cursor, int N, int E)
{
    __shared__ int part[1024];
    int r = blockIdx.x;
    const int* cnt = counts + (long)r * N;
    int* offs = r ? off1 : off0;
    int* cur  = cursor + (long)r * N;
    int t = threadIdx.x;
    int chunk = (N + 1023) / 1024;
    int a = t * chunk, b = a + chunk; if (b > N) b = N;
    int s = 0;
    for (int i = a; i < b; ++i) s += cnt[i];
    part[t] = s;
    __syncthreads();
    for (int off = 1; off < 1024; off <<= 1) {
        int v = (t >= off) ? part[t - off] : 0;
        __syncthreads();
        if (t >= off) part[t] += v;
        __syncthreads();
    }
    int p = (t == 0) ? 0 : part[t - 1];
    for (int i = a; i < b; ++i) {
        offs[i] = p; cur[i] = p; p += cnt[i];
    }
    if (t == 1023) offs[N] = E;
}

__global__ void csr_fill2(const int* __restrict__ e0p, const int* __restrict__ e1p,
                          int* __restrict__ cursor,
                          int* __restrict__ ss0, int* __restrict__ ss1, int E, int N)
{
    int e = blockIdx.x * 256 + threadIdx.x;
    if (e >= E) return;
    int r = blockIdx.y;
    const int* ed = r ? e1p : e0p;
    int* ss = r ? ss1 : ss0;
    int pos = atomicAdd(&cursor[r * N + ed[E + e]], 1);
    ss[pos] = ed[e];
}

// ============ node attention: one wave per node, 4 EDGE SLOTS (R10) ============
// Lanes: s=lane>>4 (4 edge slots), h=(lane>>3)&1 (head), l=lane&7 (8 lanes per
// (edge,head), halfx8 = 16 B each over the 64-elem k/v).
// R10: restores 4-edges-per-iteration (deg<=4 -> ONE dependent ss->gather
// chain per relation instead of two) while keeping R8's one-wave-per-node and
// R9's fp16 KV. Attn hypothesis: latency-chain-bound.
__global__ __launch_bounds__(256) void node_attn_kernel(
    const float* __restrict__ qf,          // [N][128] f32
    const _Float16* __restrict__ kvh,      // [N][512] fp16
    const int* __restrict__ off0, const int* __restrict__ ss0,
    const int* __restrict__ off1, const int* __restrict__ ss1,
    const float* __restrict__ prel,        // [2][2] (r,h)
    short* __restrict__ ohi, short* __restrict__ olo, int N)
{
    int d = blockIdx.x * 4 + (threadIdx.x >> 6);
    if (d >= N) return;
    int lane = threadIdx.x & 63;
    int s = lane >> 4, h = (lane >> 3) & 1, l = lane & 7;

    const float* qp = qf + (long)d * 128 + h * 64 + l * 8;
    float4 q4a = *(const float4*)qp;
    float4 q4b = *(const float4*)(qp + 4);

    int c0 = off0[d], b0 = off0[d + 1];
    int c1 = off1[d], b1 = off1[d + 1];
    // KV row layout: r*256 + h*128 + {k:0, v:64} + e  (fp16 elements)
    const _Float16* kp0 = kvh + h * 128 + l * 8;
    const _Float16* vp0 = kp0 + 64;
    const _Float16* kp1 = kp0 + 256;
    const _Float16* vp1 = vp0 + 256;
    float pr0 = prel[h] * 0.125f;       // includes 1/sqrt(64)
    float pr1 = prel[2 + h] * 0.125f;

    const float4 fz = {0.f, 0.f, 0.f, 0.f};
    float4 num0a = fz, num0b = fz, num1a = fz, num1b = fz;
    float den0 = 0.f, den1 = 0.f;

    while (c0 < b0 || c1 < b1) {
        // issue all gathers for both relations first (overlapped latency)
        float k0[8] = {}, v0[8] = {}, k1[8] = {}, v1[8] = {};
        bool a0 = (c0 < b0) && (c0 + s < b0);
        bool a1 = (c1 < b1) && (c1 + s < b1);
        if (a0) {
            long so = (long)ss0[c0 + s] * 512;
            halfx8 kh = *(const halfx8*)(kp0 + so);
            halfx8 vh = *(const halfx8*)(vp0 + so);
            #pragma unroll
            for (int i = 0; i < 8; ++i) { k0[i] = (float)kh[i]; v0[i] = (float)vh[i]; }
        }
        if (a1) {
            long so = (long)ss1[c1 + s] * 512;
            halfx8 kh = *(const halfx8*)(kp1 + so);
            halfx8 vh = *(const halfx8*)(vp1 + so);
            #pragma unroll
            for (int i = 0; i < 8; ++i) { k1[i] = (float)kh[i]; v1[i] = (float)vh[i]; }
        }
        if (c0 < b0) {
            float p = q4a.x*k0[0] + q4a.y*k0[1] + q4a.z*k0[2] + q4a.w*k0[3]
                    + q4b.x*k0[4] + q4b.y*k0[5] + q4b.z*k0[6] + q4b.w*k0[7];
            p += __shfl_xor(p, 1, 8);
            p += __shfl_xor(p, 2, 8);
            p += __shfl_xor(p, 4, 8);
            float w = a0 ? __expf(p * pr0) : 0.f;
            den0 += w;
            num0a.x = fmaf(w, v0[0], num0a.x); num0a.y = fmaf(w, v0[1], num0a.y);
            num0a.z = fmaf(w, v0[2], num0a.z); num0a.w = fmaf(w, v0[3], num0a.w);
            num0b.x = fmaf(w, v0[4], num0b.x); num0b.y = fmaf(w, v0[5], num0b.y);
            num0b.z = fmaf(w, v0[6], num0b.z); num0b.w = fmaf(w, v0[7], num0b.w);
            c0 += 4;                         // 4 edge slots per iter
        }
        if (c1 < b1) {
            float p = q4a.x*k1[0] + q4a.y*k1[1] + q4a.z*k1[2] + q4a.w*k1[3]
                    + q4b.x*k1[4] + q4b.y*k1[5] + q4b.z*k1[6] + q4b.w*k1[7];
            p += __shfl_xor(p, 1, 8);
            p += __shfl_xor(p, 2, 8);
            p += __shfl_xor(p, 4, 8);
            float w = a1 ? __expf(p * pr1) : 0.f;
            den1 += w;
            num1a.x = fmaf(w, v1[0], num1a.x); num1a.y = fmaf(w, v1[1], num1a.y);
            num1a.z = fmaf(w, v1[2], num1a.z); num1a.w = fmaf(w, v1[3], num1a.w);
            num1b.x = fmaf(w, v1[4], num1b.x); num1b.y = fmaf(w, v1[5], num1b.y);
            num1b.z = fmaf(w, v1[6], num1b.z); num1b.w = fmaf(w, v1[7], num1b.w);
            c1 += 4;
        }
    }

    // combine the 4 edge slots (bits 4,5 of lane): den first, then accv
    den0 += __shfl_xor(den0, 16, 64); den0 += __shfl_xor(den0, 32, 64);
    den1 += __shfl_xor(den1, 16, 64); den1 += __shfl_xor(den1, 32, 64);
    float inv0 = 1.f / (den0 + 1e-16f);
    float inv1 = 1.f / (den1 + 1e-16f);
    float4 accva, accvb;
    accva.x = num0a.x * inv0 + num1a.x * inv1;
    accva.y = num0a.y * inv0 + num1a.y * inv1;
    accva.z = num0a.z * inv0 + num1a.z * inv1;
    accva.w = num0a.w * inv0 + num1a.w * inv1;
    accvb.x = num0b.x * inv0 + num1b.x * inv1;
    accvb.y = num0b.y * inv0 + num1b.y * inv1;
    accvb.z = num0b.z * inv0 + num1b.z * inv1;
    accvb.w = num0b.w * inv0 + num1b.w * inv1;
    #pragma unroll
    for (int o = 16; o <= 32; o <<= 1) {
        accva.x += __shfl_xor(accva.x, o, 64); accva.y += __shfl_xor(accva.y, o, 64);
        accva.z += __shfl_xor(accva.z, o, 64); accva.w += __shfl_xor(accva.w, o, 64);
        accvb.x += __shfl_xor(accvb.x, o, 64); accvb.y += __shfl_xor(accvb.y, o, 64);
        accvb.z += __shfl_xor(accvb.z, o, 64); accvb.w += __shfl_xor(accvb.w, o, 64);
    }

    if (s == 0) {   // 16 lanes: both heads, 8 outputs each
        const float is2 = 0.70710678118654752f;
        float o_[8] = {accva.x, accva.y, accva.z, accva.w,
                       accvb.x, accvb.y, accvb.z, accvb.w};
        short hh[8], ll[8];
        #pragma unroll
        for (int i = 0; i < 8; ++i) {
            float g = 0.5f * o_[i] * (1.f + erff(o_[i] * is2));
            cvt_pair(g, hh[i], ll[i]);
        }
        long oo = (long)d * 128 + h * 64 + l * 8;
        *(shortx4*)(ohi + oo)     = (shortx4){hh[0], hh[1], hh[2], hh[3]};
        *(shortx4*)(ohi + oo + 4) = (shortx4){hh[4], hh[5], hh[6], hh[7]};
        *(shortx4*)(olo + oo)     = (shortx4){ll[0], ll[1], ll[2], ll[3]};
        *(shortx4*)(olo + oo + 4) = (shortx4){ll[4], ll[5], ll[6], ll[7]};
    }
}

// ============ f32 vector GEMM kept for tiny MLP ============
#define BM 64
#define BN 64
#define BK 16
__global__ __launch_bounds__(256) void gemm_bias_kernel(
    const float* __restrict__ A, int lda,
    const float* __restrict__ B, int ldb,
    const float* __restrict__ bias,
    float* __restrict__ C, int ldc,
    int M, int K, int epilogue)
{
    __shared__ float As[BK][BM + 4];
    __shared__ float Bs[BK][BN + 4];
    const int t = threadIdx.x;
    const int row0 = blockIdx.y * BM;
    const int col0 = blockIdx.x * BN;
    const int tm = (t >> 4) << 2;
    const int tn = (t & 15) << 2;
    float acc[4][4] = {};
    for (int k0 = 0; k0 < K; k0 += BK) {
        #pragma unroll
        for (int i = 0; i < 4; ++i) {
            int idx = t + i * 256;
            int m = idx >> 4, kk = idx & 15;
            int gm = row0 + m;
            As[kk][m] = (gm < M) ? A[(long)gm * lda + (k0 + kk)] : 0.f;
        }
        #pragma unroll
        for (int i = 0; i < 4; ++i) {
            int idx = t + i * 256;
            int kk = idx >> 6, n = idx & 63;
            Bs[kk][n] = B[(long)(k0 + kk) * ldb + (col0 + n)];
        }
        __syncthreads();
        #pragma unroll
        for (int kk = 0; kk < BK; ++kk) {
            float a[4], b[4];
            #pragma unroll
            for (int i = 0; i < 4; ++i) a[i] = As[kk][tm + i];
            #pragma unroll
            for (int j = 0; j < 4; ++j) b[j] = Bs[kk][tn + j];
            #pragma unroll
            for (int i = 0; i < 4; ++i)
                #pragma unroll
                for (int j = 0; j < 4; ++j)
                    acc[i][j] = fmaf(a[i], b[j], acc[i][j]);
        }
        __syncthreads();
    }
    #pragma unroll
    for (int i = 0; i < 4; ++i) {
        int gm = row0 + tm + i;
        if (gm >= M) continue;
        #pragma unroll
        for (int j = 0; j < 4; ++j) {
            int gn = col0 + tn + j;
            float v = acc[i][j];
            if (bias) v += bias[gn];
            if (epilogue >= 1) v = fmaxf(v, 0.f);
            C[(long)gm * ldc + gn] = v;
        }
    }
}

// ============ pooling (reads bf16 hi/lo planes) ============
__device__ inline int lower_bound_i(const int* __restrict__ a, int n, int v)
{
    int lo = 0, hi = n;
    while (lo < hi) { int mid = (lo + hi) >> 1; if (a[mid] < v) lo = mid + 1; else hi = mid; }
    return lo;
}

__global__ void pool_kernel(const short* __restrict__ hhi, const short* __restrict__ hlo,
                            const int* __restrict__ batch,
                            float* __restrict__ s, int N)
{
    int g = blockIdx.x, part = blockIdx.y, c = threadIdx.x;
    int start = lower_bound_i(batch, N, g);
    int end = lower_bound_i(batch, N, g + 1);
    int cnt = end - start, parts = gridDim.y;
    int chunk = (cnt + parts - 1) / parts;
    int a = start + part * chunk;
    int b = a + chunk; if (b > end) b = end;
    if (a >= b) return;
    float sum = 0.f;
    for (int n = a; n < b; ++n) {
        long o = (long)n * HDIM + c;
        sum += b2f(hhi[o]) + b2f(hlo[o]);
    }
    atomicAdd(&s[g * HDIM + c], sum);
}

__global__ void pool_finalize(const float* __restrict__ s, const int* __restrict__ batch,
                              float* __restrict__ g_out, int N)
{
    int g = blockIdx.x, c = threadIdx.x;
    int start = lower_bound_i(batch, N, g);
    int end = lower_bound_i(batch, N, g + 1);
    float cnt = (float)((end - start) > 1 ? (end - start) : 1);
    g_out[g * HDIM + c] = s[g * HDIM + c] / cnt;
}

// ============ host ============
extern "C" void kernel_launch(void* const* d_in, const int* in_sizes, int n_in,
                              void* d_out, int out_size, void* d_ws, size_t ws_size,
                              hipStream_t stream)
{
    const float* x      = (const float*)d_in[0];
    const int*   e0     = (const int*)d_in[1];
    const int*   e1     = (const int*)d_in[2];
    const int*   batch  = (const int*)d_in[3];
    const float* W_k1   = (const float*)d_in[4];
    const float* W_q1   = (const float*)d_in[5];
    const float* W_v1   = (const float*)d_in[6];
    const float* a_rel1 = (const float*)d_in[7];
    const float* m_rel1 = (const float*)d_in[8];
    const float* W_a1   = (const float*)d_in[9];
    const float* W_k23  = (const float*)d_in[10];
    const float* W_q23  = (const float*)d_in[11];
    const float* W_v23  = (const float*)d_in[12];
    const float* a_rel23= (const float*)d_in[13];
    const float* m_rel23= (const float*)d_in[14];
    const float* W_a23  = (const float*)d_in[15];
    const float* W_m1   = (const float*)d_in[16];
    const float* W_m2   = (const float*)d_in[17];
    const float* b_k1   = (const float*)d_in[18];
    const float* b_q1   = (const float*)d_in[19];
    const float* b_v1   = (const float*)d_in[20];
    const float* b_a1   = (const float*)d_in[21];
    const float* b_k23  = (const float*)d_in[22];
    const float* b_q23  = (const float*)d_in[23];
    const float* b_v23  = (const float*)d_in[24];
    const float* b_a23  = (const float*)d_in[25];
    const float* skip23 = (const float*)d_in[26];
    const float* b_m1   = (const float*)d_in[27];
    const float* b_m2   = (const float*)d_in[28];
    const float* p_rel1 = (const float*)d_in[29];
    const float* p_rel23= (const float*)d_in[30];

    const int N = N_NODES_C;
    const int E = in_sizes[1] / 2;
    const int F = in_sizes[0] / N;            // 512
    const long NP = (long)N * HDIM;           // 6.4M plane elements

    // ---- workspace layout ----
    float* ws    = (float*)d_ws;
    float*    Qf32 = ws;                                // N*128 f32 (25.6 MB)
    _Float16* KVh  = (_Float16*)(Qf32 + (long)N * 128); // N*512 fp16 (51.2 MB)
    short* ACChi = (short*)(KVh + (long)N * 512);       // 6 planes, 12.8 MB each
    short* ACClo = ACChi + NP;
    short* H1hi  = ACClo + NP;
    short* H1lo  = H1hi + NP;
    short* H2hi  = H1lo + NP;
    short* H2lo  = H2hi + NP;
    short* WThi  = H2lo + NP;                           // 640*512 max
    short* WTlo  = WThi + 640 * 512;
    short* WaThi = WTlo + 640 * 512;                    // 128*128
    short* WaTlo = WaThi + 128 * 128;
    float* B640  = (float*)(WaTlo + 128 * 128);         // 640
    float* S     = B640 + 640;
    float* GM    = S + N_GRAPHS_C * HDIM;
    float* M1    = GM + N_GRAPHS_C * HDIM;
    int*   off0  = (int*)(M1 + N_GRAPHS_C * HDIM);      // N+1
    int*   ss0   = off0 + (N + 1);                      // E
    int*   off1  = ss0 + E;                             // N+1
    int*   ss1   = off1 + (N + 1);                      // E
    int*   counts = (int*)Qf32;                         // 2N ints, alias: dead before Qf32 written
    int*   cursor = counts + 2 * N;                     // 2N
    size_t needed = (size_t)((char*)(ss1 + E) - (char*)d_ws);
    if (ws_size < needed) return;

    // ---- build CSR once, both relations per launch ----
    {
        int eb = (E + 255) / 256;
        hipMemsetAsync(counts, 0, (size_t)(2 * N) * sizeof(int), stream);
        dim3 cg(eb, 2);
        csr_count2<<<cg, 256, 0, stream>>>(e0, e1, counts, E, N);
        csr_scan2<<<2, 1024, 0, stream>>>(counts, off0, off1, cursor, N, E);
        csr_fill2<<<cg, 256, 0, stream>>>(e0, e1, cursor, ss0, ss1, E, N);
    }

    const int nrb = (N + GBM - 1) / GBM;   // 391 row blocks

    auto run_layer = [&](const void* Ain, const short* AinLo, int AF, int Fin,
                         const float* Wk, const float* bk,
                         const float* Wq, const float* bq,
                         const float* Wv, const float* bv,
                         const float* arel, const float* mrel, const float* prel,
                         const float* Wa, const float* ba,
                         const float* gate, const short* skipHi, const short* skipLo,
                         short* outHi, short* outLo) {
        dim3 bg((Fin + 255) / 256, 768);   // [640,768) = fused WaT transpose
        build_wbigT_p<<<bg, 256, 0, stream>>>(Wq, bq, Wk, bk, Wv, bv,
                                              arel, mrel, Wa,
                                              WThi, WTlo, WaThi, WaTlo, B640, Fin);
        int qb = (640 / GBN) * nrb;        // 1D grid, XCD-swizzled in-kernel
        if (AF)
            gemm_planes<1><<<qb, 256, 0, stream>>>(Ain, nullptr, Fin, WThi, WTlo, Fin,
                B640, Qf32, (short*)KVh, nullptr, N, 640, Fin, 0, nullptr, nullptr, nullptr);
        else
            gemm_planes<0><<<qb, 256, 0, stream>>>(Ain, AinLo, Fin, WThi, WTlo, Fin,
                B640, Qf32, (short*)KVh, nullptr, N, 640, Fin, 0, nullptr, nullptr, nullptr);

        node_attn_kernel<<<(N + 3) / 4, 256, 0, stream>>>(
            Qf32, KVh, off0, ss0, off1, ss1, prel, ACChi, ACClo, N);

        gemm_planes<0><<<nrb, 256, 0, stream>>>(ACChi, ACClo, 128, WaThi, WaTlo, 128,
            ba, nullptr, outHi, outLo, N, 128, 128,
            gate ? 3 : 2, gate, skipHi, skipLo);
    };

    // layer 1 (f32 x input, no skip) -> H1 planes
    run_layer(x, nullptr, 1, F, W_k1, b_k1, W_q1, b_q1, W_v1, b_v1,
              a_rel1, m_rel1, p_rel1, W_a1, b_a1,
              nullptr, nullptr, nullptr, H1hi, H1lo);
    // layer 2 (H1 planes, gated skip from H1) -> H2 planes
    run_layer(H1hi, H1lo, 0, HDIM, W_k23, b_k23, W_q23, b_q23, W_v23, b_v23,
              a_rel23, m_rel23, p_rel23, W_a23, b_a23,
              skip23, H1hi, H1lo, H2hi, H2lo);
    // layer 3 (H2 planes, gated skip from H2) -> H1 planes (reuse)
    run_layer(H2hi, H2lo, 0, HDIM, W_k23 + 16384, b_k23 + 128, W_q23 + 16384, b_q23 + 128,
              W_v23 + 16384, b_v23 + 128, a_rel23 + 16384, m_rel23 + 16384,
              p_rel23 + 4, W_a23 + 16384, b_a23 + 128,
              skip23 + 1, H2hi, H2lo, H1hi, H1lo);

    // global mean pool (batch sorted)
    hipMemsetAsync(S, 0, (size_t)N_GRAPHS_C * HDIM * sizeof(float), stream);
    dim3 pg(N_GRAPHS_C, 8);
    pool_kernel<<<pg, HDIM, 0, stream>>>(H1hi, H1lo, batch, S, N);
    pool_finalize<<<N_GRAPHS_C, HDIM, 0, stream>>>(S, batch, GM, N);

    // MLP
    {
        dim3 g1(128 / BN, 1);
        gemm_bias_kernel<<<g1, 256, 0, stream>>>(GM, 128, W_m1, 128, b_m1, M1, 128,
                                                 N_GRAPHS_C, 128, 1);
        dim3 g2(256 / BN, 1);
        gemm_bias_kernel<<<g2, 256, 0, stream>>>(M1, 128, W_m2, 256, b_m2,
                                                 (float*)d_out, 256, N_GRAPHS_C, 128, 0);
    }
}

// Round 11
// 933.626 us; speedup vs baseline: 1.0425x; 1.0425x over previous
//
#include <hip/hip_runtime.h>
#include <math.h>

#define N_NODES_C 50000
#define N_GRAPHS_C 64
#define HDIM 128

typedef short bf16x8 __attribute__((ext_vector_type(8)));
typedef short shortx4 __attribute__((ext_vector_type(4)));
typedef float floatx4 __attribute__((ext_vector_type(4)));
typedef _Float16 halfx4 __attribute__((ext_vector_type(4)));

// split f32 -> hi (truncated bf16) + lo (bf16 of exact residual)
__device__ __forceinline__ void cvt_pair(float x, short& h, short& l) {
    union { float f; unsigned u; } a; a.f = x;
    h = (short)(a.u >> 16);
    union { unsigned u; float f; } b; b.u = a.u & 0xFFFF0000u;
    union { float f; unsigned u; } c; c.f = x - b.f;   // exact residual
    l = (short)(c.u >> 16);
}

__device__ __forceinline__ float b2f(short s) {
    union { unsigned u; float f; } x; x.u = ((unsigned)(unsigned short)s) << 16;
    return x.f;
}

// async global->LDS copy, 16 B per lane, LDS dest = wave-uniform base + lane*16
__device__ __forceinline__ void gld_lds16(const void* gsrc, void* ldst) {
    __builtin_amdgcn_global_load_lds(
        (const __attribute__((address_space(1))) unsigned int*)gsrc,
        (__attribute__((address_space(3))) unsigned int*)ldst,
        16, 0, 0);
}

// ============ MFMA GEMM with global_load_lds staging ============
// R6 config FROZEN: AF32=1 dbuf 64KB (256,2); AF32=0 single 32KB (256,3).
// R11: TM template param (tile rows). TM=128: unchanged (QKV GEMMs).
// TM=64: 64x128 tile, 4 waves of 32x64 (acc[2][4]), 24 KB LDS, (256,4) ->
// out-GEMM grid 391->782 blocks: 1.5 -> 4 blocks/CU (was half-idle).
// bf16 granule XOR-swizzle both sides; XCD-bijective block swizzle.
// mode 0 writes MIXED output: cols [0,128) -> f32 Q (ld 128), cols [128,640)
// -> fp16 KV (ld 512). mode 2: relu planes. mode 3: gated-skip relu planes.
#define GBM 128
#define GBN 128
#define GBK 32

template<int AF32, int TM>
__global__ __launch_bounds__(256, AF32 ? 2 : (TM == 64 ? 4 : 3)) void gemm_planes(
    const void* __restrict__ Aptr, const short* __restrict__ Alo, int lda,
    const short* __restrict__ Bhi, const short* __restrict__ Blo, int ldbt,
    const float* __restrict__ bias,
    float* __restrict__ Cf, short* __restrict__ Chi, short* __restrict__ Clo,
    int M, int Ntot, int K,
    int mode, const float* __restrict__ skipGate,
    const short* __restrict__ Phi, const short* __restrict__ Plo)
{
    constexpr int ASZ = AF32 ? (TM * GBK * 2) : (TM * GBK);    // shorts / buffer
    constexpr int BSZ = GBN * GBK;
    constexpr int NB  = AF32 ? 2 : 1;                          // LDS buffers
    constexpr int NI  = TM / 32;                               // A fragments/wave
    constexpr int WR  = TM / 2;                                // rows per wm group
    __shared__ __align__(16) short AsH[NB * ASZ];
    __shared__ __align__(16) short AsL[AF32 ? 8 : ASZ];
    __shared__ __align__(16) short BsH[NB * BSZ];
    __shared__ __align__(16) short BsL[NB * BSZ];

    const int t = threadIdx.x;
    const int lane = t & 63;
    const int wave = t >> 6;
    const int wm = wave & 1, wn = wave >> 1;
    const int quad = lane >> 4, l15 = lane & 15;

    // XCD-bijective chunked swizzle (valid for any nwg), column-fastest decode
    const int nwg = gridDim.x, bid0 = blockIdx.x;
    const int qq = nwg >> 3, rr = nwg & 7;
    const int xcd = bid0 & 7, idx = bid0 >> 3;
    const int swz = (xcd < rr ? xcd * (qq + 1)
                              : rr * (qq + 1) + (xcd - rr) * qq) + idx;
    const int ncb = (Ntot + GBN - 1) / GBN;
    const long row0 = (long)(swz / ncb) * TM;
    const long col0 = (long)(swz % ncb) * GBN;

    floatx4 acc[NI][4];
    #pragma unroll
    for (int i = 0; i < NI; ++i)
        #pragma unroll
        for (int j = 0; j < 4; ++j)
            acc[i][j] = (floatx4){0.f, 0.f, 0.f, 0.f};

    const int nkt = K / GBK;

    auto stage = [&](int buf, int k0) {
        if constexpr (AF32) {
            const float* Af = (const float*)Aptr;
            int r8 = lane >> 3, kc8 = lane & 7;
            #pragma unroll
            for (int cc = 0; cc < 4; ++cc) {
                int ch = wave * 4 + cc;
                long gr = row0 + ch * 8 + r8;
                if (gr > M - 1) gr = M - 1;
                gld_lds16(Af + gr * lda + k0 + ((kc8 ^ r8) << 2),
                          AsH + buf * ASZ + ch * 512);
            }
        } else {
            const short* Ahi = (const short*)Aptr;
            int r16 = lane >> 2, g4 = lane & 3;
            int gs = (g4 ^ ((r16 >> 1) & 3)) * 8;   // granule swizzle (src side)
            #pragma unroll
            for (int cc = 0; cc < TM / 64; ++cc) {  // 2 chunks (TM=128) or 1 (TM=64)
                int ch = wave * (TM / 64) + cc;
                long gr = row0 + ch * 16 + r16;
                if (gr > M - 1) gr = M - 1;
                long go = gr * lda + k0 + gs;
                gld_lds16(Ahi + go, AsH + ch * 512);
                gld_lds16(Alo + go, AsL + ch * 512);
            }
        }
        {
            int r16 = lane >> 2, g4 = lane & 3;
            int gs = (g4 ^ ((r16 >> 1) & 3)) * 8;   // granule swizzle (src side)
            #pragma unroll
            for (int cc = 0; cc < 2; ++cc) {
                int ch = wave * 2 + cc;
                long gc = col0 + ch * 16 + r16;
                if (gc > Ntot - 1) gc = Ntot - 1;
                long go = gc * ldbt + k0 + gs;
                gld_lds16(Bhi + go, BsH + buf * BSZ + ch * 512);
                gld_lds16(Blo + go, BsL + buf * BSZ + ch * 512);
            }
        }
    };

    auto compute = [&](int buf) {
        bf16x8 aH[NI], aL[NI], bH[4], bL[4];
        if constexpr (AF32) {
            #pragma unroll
            for (int i = 0; i < NI; ++i) {
                int row = wm * WR + i * 16 + l15;
                const float* fr = (const float*)(AsH + buf * ASZ) + row * 32;
                int x7 = row & 7;
                float4 f0 = *(const float4*)(fr + (((quad * 2)     ^ x7) << 2));
                float4 f1 = *(const float4*)(fr + (((quad * 2 + 1) ^ x7) << 2));
                short h0,h1,h2,h3,h4,h5,h6,h7, l0,l1,l2,l3,l4,l5,l6,l7;
                cvt_pair(f0.x,h0,l0); cvt_pair(f0.y,h1,l1);
                cvt_pair(f0.z,h2,l2); cvt_pair(f0.w,h3,l3);
                cvt_pair(f1.x,h4,l4); cvt_pair(f1.y,h5,l5);
                cvt_pair(f1.z,h6,l6); cvt_pair(f1.w,h7,l7);
                aH[i] = (bf16x8){h0,h1,h2,h3,h4,h5,h6,h7};
                aL[i] = (bf16x8){l0,l1,l2,l3,l4,l5,l6,l7};
            }
        } else {
            #pragma unroll
            for (int i = 0; i < NI; ++i) {
                int row = wm * WR + i * 16 + l15;
                int off = row * 32 + ((quad ^ ((row >> 1) & 3)) * 8);
                aH[i] = *(const bf16x8*)&AsH[off];
                aL[i] = *(const bf16x8*)&AsL[off];
            }
        }
        #pragma unroll
        for (int j = 0; j < 4; ++j) {
            int row = wn * 64 + j * 16 + l15;
            int off = buf * BSZ + row * 32 + ((quad ^ ((row >> 1) & 3)) * 8);
            bH[j] = *(const bf16x8*)&BsH[off];
            bL[j] = *(const bf16x8*)&BsL[off];
        }
        #pragma unroll
        for (int i = 0; i < NI; ++i)
            #pragma unroll
            for (int j = 0; j < 4; ++j) {
                acc[i][j] = __builtin_amdgcn_mfma_f32_16x16x32_bf16(aH[i], bH[j], acc[i][j], 0, 0, 0);
                acc[i][j] = __builtin_amdgcn_mfma_f32_16x16x32_bf16(aH[i], bL[j], acc[i][j], 0, 0, 0);
                acc[i][j] = __builtin_amdgcn_mfma_f32_16x16x32_bf16(aL[i], bH[j], acc[i][j], 0, 0, 0);
            }
    };

    if constexpr (AF32) {
        stage(0, 0);
        int cur = 0;
        for (int kt = 0; kt < nkt; ++kt) {
            __syncthreads();
            if (kt + 1 < nkt) stage(cur ^ 1, (kt + 1) * GBK);
            compute(cur);
            cur ^= 1;
        }
    } else {
        for (int kt = 0; kt < nkt; ++kt) {
            stage(0, kt * GBK);
            __syncthreads();
            compute(0);
            __syncthreads();
        }
    }

    float gate = 0.f;
    if (mode == 3) gate = 1.f / (1.f + __expf(-skipGate[0]));
    _Float16* kvout = (_Float16*)Chi;   // mode 0 fp16 KV destination

    #pragma unroll
    for (int i = 0; i < NI; ++i) {
        #pragma unroll
        for (int r4 = 0; r4 < 4; ++r4) {
            long grow = row0 + wm * WR + i * 16 + quad * 4 + r4;
            if (grow >= M) continue;
            #pragma unroll
            for (int j = 0; j < 4; ++j) {
                long gcol = col0 + wn * 64 + j * 16 + l15;
                if (gcol >= Ntot) continue;
                float v = acc[i][j][r4];
                if (bias) v += bias[gcol];
                if (mode == 0) {
                    if (gcol < 128) Cf[grow * 128 + gcol] = v;
                    else kvout[grow * 512 + (gcol - 128)] = (_Float16)v;
                } else {
                    if (mode == 3) {
                        long po = grow * 128 + gcol;
                        float pv = b2f(Phi[po]) + b2f(Plo[po]);
                        v = gate * v + (1.f - gate) * pv;
                    }
                    v = fmaxf(v, 0.f);
                    short hh, ll; cvt_pair(v, hh, ll);
                    Chi[grow * 128 + gcol] = hh;
                    Clo[grow * 128 + gcol] = ll;
                }
            }
        }
    }
}

// ============ build fused WbigT[640, F] planes + bias640 + WaT transpose ============
// Column layout: [0,128) q | per (relation r, head h) contiguous 128-col
// block: k_rh (64) then v_rh (64). Block order: r0h0, r0h1, r1h0, r1h1.
// blockIdx.y in [640,768) writes the WaT transpose planes (fused).
__global__ __launch_bounds__(256) void build_wbigT_p(
    const float* __restrict__ Wq, const float* __restrict__ bq,
    const float* __restrict__ Wk, const float* __restrict__ bk,
    const float* __restrict__ Wv, const float* __restrict__ bv,
    const float* __restrict__ arel, const float* __restrict__ mrel,
    const float* __restrict__ Wa,
    short* __restrict__ WThi, short* __restrict__ WTlo,
    short* __restrict__ WaThi, short* __restrict__ WaTlo,
    float* __restrict__ bias, int F)
{
    __shared__ float Trow[64];
    int c = blockIdx.y;
    int f = blockIdx.x * 256 + threadIdx.x;

    if (c >= 640) {                       // fused Wa transpose
        int cc = c - 640;                 // 0..127
        if (blockIdx.x == 0 && threadIdx.x < 128) {
            int ff = threadIdx.x;
            short hh, ll; cvt_pair(Wa[(long)ff * 128 + cc], hh, ll);
            WaThi[cc * 128 + ff] = hh;
            WaTlo[cc * 128 + ff] = ll;
        }
        return;
    }

    float w = 0.f, b = 0.f;
    if (c < 128) {
        if (f < F) w = Wq[(long)f * 128 + c];
        b = bq[c];
    } else {
        int cc = c - 128;              // 0..511
        int r  = cc >> 8;              // relation
        int hb = cc & 255;             // within relation
        int h  = hb >> 7;              // head
        int kv = (hb >> 6) & 1;        // 0 = k, 1 = v
        int e  = hb & 63;              // element within head
        const float* Wsrc = kv ? Wv : Wk;
        const float* bsrc = kv ? bv : bk;
        const float* T    = kv ? mrel : arel;
        const float* Tr = T + (long)(r * 2 + h) * 4096 + e;
        if (threadIdx.x < 64) Trow[threadIdx.x] = Tr[(long)threadIdx.x * 64];
        __syncthreads();
        if (f < F) {
            const float* Wrow = Wsrc + (long)f * 128 + h * 64;
            float s = 0.f;
            #pragma unroll 4
            for (int d = 0; d < 64; ++d) s = fmaf(Wrow[d], Trow[d], s);
            w = s;
        }
        if (f == 0) {
            const float* brow = bsrc + h * 64;
            float sb = 0.f;
            for (int d = 0; d < 64; ++d) sb = fmaf(brow[d], Trow[d], sb);
            b = sb;
        }
    }
    if (f < F) {
        short hh, ll; cvt_pair(w, hh, ll);
        WThi[(long)c * F + f] = hh;
        WTlo[(long)c * F + f] = ll;
    }
    if (f == 0) bias[c] = b;
}

// ============ CSR build, both relations per launch (blockIdx.y = r) ============
__global__ void csr_count2(const int* __restrict__ e0p, const int* __restrict__ e1p,
                           int* __restrict__ counts, int E, int N)
{
    int e = blockIdx.x * 256 + threadIdx.x;
    int r = blockIdx.y;
    const int* dst = (r ? e1p : e0p) + E;
    if (e < E) atomicAdd(&counts[r * N + dst[e]], 1);
}

__global__ __launch_bounds__(1024) void csr_scan2(
    const int* __restrict__ counts,
    int* __restrict__ off0, int* __restrict__ off1,
    int* __restrict__ cursor, int N, int E)
{
    __shared__ int part[1024];
    int r = blockIdx.x;
    const int* cnt = counts + (long)r * N;
    int* offs = r ? off1 : off0;
    int* cur  = cursor + (long)r * N;
    int t = threadIdx.x;
    int chunk = (N + 1023) / 1024;
    int a = t * chunk, b = a + chunk; if (b > N) b = N;
    int s = 0;
    for (int i = a; i < b; ++i) s += cnt[i];
    part[t] = s;
    __syncthreads();
    for (int off = 1; off < 1024; off <<= 1) {
        int v = (t >= off) ? part[t - off] : 0;
        __syncthreads();
        if (t >= off) part[t] += v;
        __syncthreads();
    }
    int p = (t == 0) ? 0 : part[t - 1];
    for (int i = a; i < b; ++i) {
        offs[i] = p; cur[i] = p; p += cnt[i];
    }
    if (t == 1023) offs[N] = E;
}

__global__ void csr_fill2(const int* __restrict__ e0p, const int* __restrict__ e1p,
                          int* __restrict__ cursor,
                          int* __restrict__ ss0, int* __restrict__ ss1, int E, int N)
{
    int e = blockIdx.x * 256 + threadIdx.x;
    if (e >= E) return;
    int r = blockIdx.y;
    const int* ed = r ? e1p : e0p;
    int* ss = r ? ss1 : ss0;
    int pos = atomicAdd(&cursor[r * N + ed[E + e]], 1);
    ss[pos] = ed[e];
}

// ============ node attention: one wave per node, both heads (R9 version) ============
// R11: reverted to the R9 form (measured best E2E 955; R10's 4-slot variant
// regressed). fp16 KV gathers (512 B/edge both heads), 2 edge slots,
// epilogue xor-32 butterfly only.
__global__ __launch_bounds__(256) void node_attn_kernel(
    const float* __restrict__ qf,          // [N][128] f32
    const _Float16* __restrict__ kvh,      // [N][512] fp16
    const int* __restrict__ off0, const int* __restrict__ ss0,
    const int* __restrict__ off1, const int* __restrict__ ss1,
    const float* __restrict__ prel,        // [2][2] (r,h)
    short* __restrict__ ohi, short* __restrict__ olo, int N)
{
    int d = blockIdx.x * 4 + (threadIdx.x >> 6);
    if (d >= N) return;
    int lane = threadIdx.x & 63;
    int g = lane >> 5, h = (lane >> 4) & 1, l = lane & 15;

    float4 q4 = *(const float4*)(qf + (long)d * 128 + h * 64 + l * 4);

    int c0 = off0[d], b0 = off0[d + 1];
    int c1 = off1[d], b1 = off1[d + 1];
    // KV row layout: r*256 + h*128 + {k:0, v:64} + e  (fp16 elements)
    const _Float16* kp0 = kvh + h * 128 + l * 4;
    const _Float16* vp0 = kp0 + 64;
    const _Float16* kp1 = kp0 + 256;
    const _Float16* vp1 = vp0 + 256;
    float pr0 = prel[h] * 0.125f;       // includes 1/sqrt(64)
    float pr1 = prel[2 + h] * 0.125f;

    const float4 fz = {0.f, 0.f, 0.f, 0.f};
    float4 num0 = fz, num1 = fz;
    float den0 = 0.f, den1 = 0.f;

    while (c0 < b0 || c1 < b1) {
        float4 k0 = fz, v0 = fz, k1 = fz, v1 = fz;
        bool a0 = (c0 < b0) && (c0 + g < b0);
        bool a1 = (c1 < b1) && (c1 + g < b1);
        if (a0) {
            long so = (long)ss0[c0 + g] * 512;
            halfx4 kh = *(const halfx4*)(kp0 + so);
            halfx4 vh = *(const halfx4*)(vp0 + so);
            k0.x = (float)kh[0]; k0.y = (float)kh[1];
            k0.z = (float)kh[2]; k0.w = (float)kh[3];
            v0.x = (float)vh[0]; v0.y = (float)vh[1];
            v0.z = (float)vh[2]; v0.w = (float)vh[3];
        }
        if (a1) {
            long so = (long)ss1[c1 + g] * 512;
            halfx4 kh = *(const halfx4*)(kp1 + so);
            halfx4 vh = *(const halfx4*)(vp1 + so);
            k1.x = (float)kh[0]; k1.y = (float)kh[1];
            k1.z = (float)kh[2]; k1.w = (float)kh[3];
            v1.x = (float)vh[0]; v1.y = (float)vh[1];
            v1.z = (float)vh[2]; v1.w = (float)vh[3];
        }
        if (c0 < b0) {
            float p = q4.x*k0.x + q4.y*k0.y + q4.z*k0.z + q4.w*k0.w;
            p += __shfl_xor(p, 1, 16);
            p += __shfl_xor(p, 2, 16);
            p += __shfl_xor(p, 4, 16);
            p += __shfl_xor(p, 8, 16);
            float w = a0 ? __expf(p * pr0) : 0.f;
            den0 += w;
            num0.x = fmaf(w, v0.x, num0.x);
            num0.y = fmaf(w, v0.y, num0.y);
            num0.z = fmaf(w, v0.z, num0.z);
            num0.w = fmaf(w, v0.w, num0.w);
            c0 += 2;                         // 2 edge slots per iter
        }
        if (c1 < b1) {
            float p = q4.x*k1.x + q4.y*k1.y + q4.z*k1.z + q4.w*k1.w;
            p += __shfl_xor(p, 1, 16);
            p += __shfl_xor(p, 2, 16);
            p += __shfl_xor(p, 4, 16);
            p += __shfl_xor(p, 8, 16);
            float w = a1 ? __expf(p * pr1) : 0.f;
            den1 += w;
            num1.x = fmaf(w, v1.x, num1.x);
            num1.y = fmaf(w, v1.y, num1.y);
            num1.z = fmaf(w, v1.z, num1.z);
            num1.w = fmaf(w, v1.w, num1.w);
            c1 += 2;
        }
    }

    // combine the two edge slots (g=0 vs g=1): xor-32 butterfly only
    den0 += __shfl_xor(den0, 32, 64);
    den1 += __shfl_xor(den1, 32, 64);
    float inv0 = 1.f / (den0 + 1e-16f);
    float inv1 = 1.f / (den1 + 1e-16f);
    float4 accv;
    accv.x = num0.x * inv0 + num1.x * inv1;
    accv.y = num0.y * inv0 + num1.y * inv1;
    accv.z = num0.z * inv0 + num1.z * inv1;
    accv.w = num0.w * inv0 + num1.w * inv1;
    accv.x += __shfl_xor(accv.x, 32, 64);
    accv.y += __shfl_xor(accv.y, 32, 64);
    accv.z += __shfl_xor(accv.z, 32, 64);
    accv.w += __shfl_xor(accv.w, 32, 64);

    if (g == 0) {   // 32 lanes: both heads' outputs
        const float is2 = 0.70710678118654752f;
        float o0 = 0.5f * accv.x * (1.f + erff(accv.x * is2));
        float o1 = 0.5f * accv.y * (1.f + erff(accv.y * is2));
        float o2 = 0.5f * accv.z * (1.f + erff(accv.z * is2));
        float o3 = 0.5f * accv.w * (1.f + erff(accv.w * is2));
        short h0,h1,h2,h3, l0,l1,l2,l3;
        cvt_pair(o0,h0,l0); cvt_pair(o1,h1,l1);
        cvt_pair(o2,h2,l2); cvt_pair(o3,h3,l3);
        long oo = (long)d * 128 + h * 64 + l * 4;
        *(shortx4*)(ohi + oo) = (shortx4){h0,h1,h2,h3};
        *(shortx4*)(olo + oo) = (shortx4){l0,l1,l2,l3};
    }
}

// ============ f32 vector GEMM kept for tiny MLP ============
#define BM 64
#define BN 64
#define BK 16
__global__ __launch_bounds__(256) void gemm_bias_kernel(
    const float* __restrict__ A, int lda,
    const float* __restrict__ B, int ldb,
    const float* __restrict__ bias,
    float* __restrict__ C, int ldc,
    int M, int K, int epilogue)
{
    __shared__ float As[BK][BM + 4];
    __shared__ float Bs[BK][BN + 4];
    const int t = threadIdx.x;
    const int row0 = blockIdx.y * BM;
    const int col0 = blockIdx.x * BN;
    const int tm = (t >> 4) << 2;
    const int tn = (t & 15) << 2;
    float acc[4][4] = {};
    for (int k0 = 0; k0 < K; k0 += BK) {
        #pragma unroll
        for (int i = 0; i < 4; ++i) {
            int idx = t + i * 256;
            int m = idx >> 4, kk = idx & 15;
            int gm = row0 + m;
            As[kk][m] = (gm < M) ? A[(long)gm * lda + (k0 + kk)] : 0.f;
        }
        #pragma unroll
        for (int i = 0; i < 4; ++i) {
            int idx = t + i * 256;
            int kk = idx >> 6, n = idx & 63;
            Bs[kk][n] = B[(long)(k0 + kk) * ldb + (col0 + n)];
        }
        __syncthreads();
        #pragma unroll
        for (int kk = 0; kk < BK; ++kk) {
            float a[4], b[4];
            #pragma unroll
            for (int i = 0; i < 4; ++i) a[i] = As[kk][tm + i];
            #pragma unroll
            for (int j = 0; j < 4; ++j) b[j] = Bs[kk][tn + j];
            #pragma unroll
            for (int i = 0; i < 4; ++i)
                #pragma unroll
                for (int j = 0; j < 4; ++j)
                    acc[i][j] = fmaf(a[i], b[j], acc[i][j]);
        }
        __syncthreads();
    }
    #pragma unroll
    for (int i = 0; i < 4; ++i) {
        int gm = row0 + tm + i;
        if (gm >= M) continue;
        #pragma unroll
        for (int j = 0; j < 4; ++j) {
            int gn = col0 + tn + j;
            float v = acc[i][j];
            if (bias) v += bias[gn];
            if (epilogue >= 1) v = fmaxf(v, 0.f);
            C[(long)gm * ldc + gn] = v;
        }
    }
}

// ============ pooling (reads bf16 hi/lo planes) ============
__device__ inline int lower_bound_i(const int* __restrict__ a, int n, int v)
{
    int lo = 0, hi = n;
    while (lo < hi) { int mid = (lo + hi) >> 1; if (a[mid] < v) lo = mid + 1; else hi = mid; }
    return lo;
}

__global__ void pool_kernel(const short* __restrict__ hhi, const short* __restrict__ hlo,
                            const int* __restrict__ batch,
                            float* __restrict__ s, int N)
{
    int g = blockIdx.x, part = blockIdx.y, c = threadIdx.x;
    int start = lower_bound_i(batch, N, g);
    int end = lower_bound_i(batch, N, g + 1);
    int cnt = end - start, parts = gridDim.y;
    int chunk = (cnt + parts - 1) / parts;
    int a = start + part * chunk;
    int b = a + chunk; if (b > end) b = end;
    if (a >= b) return;
    float sum = 0.f;
    for (int n = a; n < b; ++n) {
        long o = (long)n * HDIM + c;
        sum += b2f(hhi[o]) + b2f(hlo[o]);
    }
    atomicAdd(&s[g * HDIM + c], sum);
}

__global__ void pool_finalize(const float* __restrict__ s, const int* __restrict__ batch,
                              float* __restrict__ g_out, int N)
{
    int g = blockIdx.x, c = threadIdx.x;
    int start = lower_bound_i(batch, N, g);
    int end = lower_bound_i(batch, N, g + 1);
    float cnt = (float)((end - start) > 1 ? (end - start) : 1);
    g_out[g * HDIM + c] = s[g * HDIM + c] / cnt;
}

// ============ host ============
extern "C" void kernel_launch(void* const* d_in, const int* in_sizes, int n_in,
                              void* d_out, int out_size, void* d_ws, size_t ws_size,
                              hipStream_t stream)
{
    const float* x      = (const float*)d_in[0];
    const int*   e0     = (const int*)d_in[1];
    const int*   e1     = (const int*)d_in[2];
    const int*   batch  = (const int*)d_in[3];
    const float* W_k1   = (const float*)d_in[4];
    const float* W_q1   = (const float*)d_in[5];
    const float* W_v1   = (const float*)d_in[6];
    const float* a_rel1 = (const float*)d_in[7];
    const float* m_rel1 = (const float*)d_in[8];
    const float* W_a1   = (const float*)d_in[9];
    const float* W_k23  = (const float*)d_in[10];
    const float* W_q23  = (const float*)d_in[11];
    const float* W_v23  = (const float*)d_in[12];
    const float* a_rel23= (const float*)d_in[13];
    const float* m_rel23= (const float*)d_in[14];
    const float* W_a23  = (const float*)d_in[15];
    const float* W_m1   = (const float*)d_in[16];
    const float* W_m2   = (const float*)d_in[17];
    const float* b_k1   = (const float*)d_in[18];
    const float* b_q1   = (const float*)d_in[19];
    const float* b_v1   = (const float*)d_in[20];
    const float* b_a1   = (const float*)d_in[21];
    const float* b_k23  = (const float*)d_in[22];
    const float* b_q23  = (const float*)d_in[23];
    const float* b_v23  = (const float*)d_in[24];
    const float* b_a23  = (const float*)d_in[25];
    const float* skip23 = (const float*)d_in[26];
    const float* b_m1   = (const float*)d_in[27];
    const float* b_m2   = (const float*)d_in[28];
    const float* p_rel1 = (const float*)d_in[29];
    const float* p_rel23= (const float*)d_in[30];

    const int N = N_NODES_C;
    const int E = in_sizes[1] / 2;
    const int F = in_sizes[0] / N;            // 512
    const long NP = (long)N * HDIM;           // 6.4M plane elements

    // ---- workspace layout ----
    float* ws    = (float*)d_ws;
    float*    Qf32 = ws;                                // N*128 f32 (25.6 MB)
    _Float16* KVh  = (_Float16*)(Qf32 + (long)N * 128); // N*512 fp16 (51.2 MB)
    short* ACChi = (short*)(KVh + (long)N * 512);       // 6 planes, 12.8 MB each
    short* ACClo = ACChi + NP;
    short* H1hi  = ACClo + NP;
    short* H1lo  = H1hi + NP;
    short* H2hi  = H1lo + NP;
    short* H2lo  = H2hi + NP;
    short* WThi  = H2lo + NP;                           // 640*512 max
    short* WTlo  = WThi + 640 * 512;
    short* WaThi = WTlo + 640 * 512;                    // 128*128
    short* WaTlo = WaThi + 128 * 128;
    float* B640  = (float*)(WaTlo + 128 * 128);         // 640
    float* S     = B640 + 640;
    float* GM    = S + N_GRAPHS_C * HDIM;
    float* M1    = GM + N_GRAPHS_C * HDIM;
    int*   off0  = (int*)(M1 + N_GRAPHS_C * HDIM);      // N+1
    int*   ss0   = off0 + (N + 1);                      // E
    int*   off1  = ss0 + E;                             // N+1
    int*   ss1   = off1 + (N + 1);                      // E
    int*   counts = (int*)Qf32;                         // 2N ints, alias: dead before Qf32 written
    int*   cursor = counts + 2 * N;                     // 2N
    size_t needed = (size_t)((char*)(ss1 + E) - (char*)d_ws);
    if (ws_size < needed) return;

    // ---- build CSR once, both relations per launch ----
    {
        int eb = (E + 255) / 256;
        hipMemsetAsync(counts, 0, (size_t)(2 * N) * sizeof(int), stream);
        dim3 cg(eb, 2);
        csr_count2<<<cg, 256, 0, stream>>>(e0, e1, counts, E, N);
        csr_scan2<<<2, 1024, 0, stream>>>(counts, off0, off1, cursor, N, E);
        csr_fill2<<<cg, 256, 0, stream>>>(e0, e1, cursor, ss0, ss1, E, N);
    }

    const int nrb   = (N + GBM - 1) / GBM;   // 391 row blocks (TM=128)
    const int nrb64 = (N + 63) / 64;         // 782 row blocks (TM=64)

    auto run_layer = [&](const void* Ain, const short* AinLo, int AF, int Fin,
                         const float* Wk, const float* bk,
                         const float* Wq, const float* bq,
                         const float* Wv, const float* bv,
                         const float* arel, const float* mrel, const float* prel,
                         const float* Wa, const float* ba,
                         const float* gate, const short* skipHi, const short* skipLo,
                         short* outHi, short* outLo) {
        dim3 bg((Fin + 255) / 256, 768);   // [640,768) = fused WaT transpose
        build_wbigT_p<<<bg, 256, 0, stream>>>(Wq, bq, Wk, bk, Wv, bv,
                                              arel, mrel, Wa,
                                              WThi, WTlo, WaThi, WaTlo, B640, Fin);
        int qb = (640 / GBN) * nrb;        // 1D grid, XCD-swizzled in-kernel
        if (AF)
            gemm_planes<1, 128><<<qb, 256, 0, stream>>>(Ain, nullptr, Fin, WThi, WTlo, Fin,
                B640, Qf32, (short*)KVh, nullptr, N, 640, Fin, 0, nullptr, nullptr, nullptr);
        else
            gemm_planes<0, 128><<<qb, 256, 0, stream>>>(Ain, AinLo, Fin, WThi, WTlo, Fin,
                B640, Qf32, (short*)KVh, nullptr, N, 640, Fin, 0, nullptr, nullptr, nullptr);

        node_attn_kernel<<<(N + 3) / 4, 256, 0, stream>>>(
            Qf32, KVh, off0, ss0, off1, ss1, prel, ACChi, ACClo, N);

        // out-GEMM: TM=64 variant -> 782 blocks at 4 blocks/CU (full machine)
        gemm_planes<0, 64><<<nrb64, 256, 0, stream>>>(ACChi, ACClo, 128, WaThi, WaTlo, 128,
            ba, nullptr, outHi, outLo, N, 128, 128,
            gate ? 3 : 2, gate, skipHi, skipLo);
    };

    // layer 1 (f32 x input, no skip) -> H1 planes
    run_layer(x, nullptr, 1, F, W_k1, b_k1, W_q1, b_q1, W_v1, b_v1,
              a_rel1, m_rel1, p_rel1, W_a1, b_a1,
              nullptr, nullptr, nullptr, H1hi, H1lo);
    // layer 2 (H1 planes, gated skip from H1) -> H2 planes
    run_layer(H1hi, H1lo, 0, HDIM, W_k23, b_k23, W_q23, b_q23, W_v23, b_v23,
              a_rel23, m_rel23, p_rel23, W_a23, b_a23,
              skip23, H1hi, H1lo, H2hi, H2lo);
    // layer 3 (H2 planes, gated skip from H2) -> H1 planes (reuse)
    run_layer(H2hi, H2lo, 0, HDIM, W_k23 + 16384, b_k23 + 128, W_q23 + 16384, b_q23 + 128,
              W_v23 + 16384, b_v23 + 128, a_rel23 + 16384, m_rel23 + 16384,
              p_rel23 + 4, W_a23 + 16384, b_a23 + 128,
              skip23 + 1, H2hi, H2lo, H1hi, H1lo);

    // global mean pool (batch sorted)
    hipMemsetAsync(S, 0, (size_t)N_GRAPHS_C * HDIM * sizeof(float), stream);
    dim3 pg(N_GRAPHS_C, 8);
    pool_kernel<<<pg, HDIM, 0, stream>>>(H1hi, H1lo, batch, S, N);
    pool_finalize<<<N_GRAPHS_C, HDIM, 0, stream>>>(S, batch, GM, N);

    // MLP
    {
        dim3 g1(128 / BN, 1);
        gemm_bias_kernel<<<g1, 256, 0, stream>>>(GM, 128, W_m1, 128, b_m1, M1, 128,
                                                 N_GRAPHS_C, 128, 1);
        dim3 g2(256 / BN, 1);
        gemm_bias_kernel<<<g2, 256, 0, stream>>>(M1, 128, W_m2, 256, b_m2,
                                                 (float*)d_out, 256, N_GRAPHS_C, 128, 0);
    }
}

// Round 12
// 810.066 us; speedup vs baseline: 1.2015x; 1.1525x over previous
//
#include <hip/hip_runtime.h>
#include <math.h>

#define N_NODES_C 50000
#define N_GRAPHS_C 64
#define HDIM 128

typedef short bf16x8 __attribute__((ext_vector_type(8)));
typedef short shortx4 __attribute__((ext_vector_type(4)));
typedef float floatx4 __attribute__((ext_vector_type(4)));
typedef _Float16 halfx4 __attribute__((ext_vector_type(4)));

// f32 -> bf16 round-to-nearest-even
__device__ __forceinline__ short cvt_rn(float x) {
    union { float f; unsigned u; } a; a.f = x;
    unsigned r = a.u + 0x7FFFu + ((a.u >> 16) & 1u);
    return (short)(r >> 16);
}

__device__ __forceinline__ float b2f(short s) {
    union { unsigned u; float f; } x; x.u = ((unsigned)(unsigned short)s) << 16;
    return x.f;
}

// async global->LDS copy, 16 B per lane, LDS dest = wave-uniform base + lane*16
__device__ __forceinline__ void gld_lds16(const void* gsrc, void* ldst) {
    __builtin_amdgcn_global_load_lds(
        (const __attribute__((address_space(1))) unsigned int*)gsrc,
        (__attribute__((address_space(3))) unsigned int*)ldst,
        16, 0, 0);
}

// ============ MFMA GEMM, SINGLE bf16 plane (R12) ============
// R12 rationale: graph mean-pool averages ~780 nodes -> node-level errors
// attenuate ~1/sqrt(780)=0.036 before the output MLP (evidence: R9's fp16 k/v
// rel-err 5e-4 left absmax bit-identical at the 2^-14 bf16 output floor).
// Single-plane bf16 RTN GEMM (1 MFMA per tile op, was 3) keeps pooled error
// ~1e-4 and cuts MFMA 3x, staging ~2x, lo-LDS entirely.
//   AF32=1 (layer-1 QKV): dbuf 2-phase, 48 KB LDS, (256,3)
//   AF32=0 TM=128 (QKV 2/3): single-buffer 16 KB, (256,3)
//   AF32=0 TM=64 (out-GEMM): single-buffer 12 KB, (256,4), grid 782
// bf16 granule XOR-swizzle both sides; XCD-bijective block swizzle (frozen).
// mode 0: cols [0,128) -> f32 Q (ld 128); cols [128,640) -> fp16 KV (ld 512)
// mode 2: Chi = bf16 relu(v + bias)            (ldc = 128)
// mode 3: Chi = bf16 relu(gate*v+bias + (1-gate)*prev_hi)
#define GBM 128
#define GBN 128
#define GBK 32

template<int AF32, int TM>
__global__ __launch_bounds__(256, TM == 64 ? 4 : 3) void gemm_planes(
    const void* __restrict__ Aptr, int lda,
    const short* __restrict__ Bhi, int ldbt,
    const float* __restrict__ bias,
    float* __restrict__ Cf, short* __restrict__ Chi,
    int M, int Ntot, int K,
    int mode, const float* __restrict__ skipGate,
    const short* __restrict__ Phi)
{
    constexpr int ASZ = AF32 ? (TM * GBK * 2) : (TM * GBK);    // shorts / buffer
    constexpr int BSZ = GBN * GBK;
    constexpr int NB  = AF32 ? 2 : 1;                          // LDS buffers
    constexpr int NI  = TM / 32;                               // A fragments/wave
    constexpr int WR  = TM / 2;                                // rows per wm group
    __shared__ __align__(16) short AsH[NB * ASZ];
    __shared__ __align__(16) short BsH[NB * BSZ];

    const int t = threadIdx.x;
    const int lane = t & 63;
    const int wave = t >> 6;
    const int wm = wave & 1, wn = wave >> 1;
    const int quad = lane >> 4, l15 = lane & 15;

    // XCD-bijective chunked swizzle (valid for any nwg), column-fastest decode
    const int nwg = gridDim.x, bid0 = blockIdx.x;
    const int qq = nwg >> 3, rr = nwg & 7;
    const int xcd = bid0 & 7, idx = bid0 >> 3;
    const int swz = (xcd < rr ? xcd * (qq + 1)
                              : rr * (qq + 1) + (xcd - rr) * qq) + idx;
    const int ncb = (Ntot + GBN - 1) / GBN;
    const long row0 = (long)(swz / ncb) * TM;
    const long col0 = (long)(swz % ncb) * GBN;

    floatx4 acc[NI][4];
    #pragma unroll
    for (int i = 0; i < NI; ++i)
        #pragma unroll
        for (int j = 0; j < 4; ++j)
            acc[i][j] = (floatx4){0.f, 0.f, 0.f, 0.f};

    const int nkt = K / GBK;

    auto stage = [&](int buf, int k0) {
        if constexpr (AF32) {
            // f32 A tile TM x 32 = 16 KB, 16 chunks of 1 KB (8 rows each),
            // kc8^r8 granule swizzle: fragment reads ~conflict-free
            const float* Af = (const float*)Aptr;
            int r8 = lane >> 3, kc8 = lane & 7;
            #pragma unroll
            for (int cc = 0; cc < 4; ++cc) {
                int ch = wave * 4 + cc;
                long gr = row0 + ch * 8 + r8;
                if (gr > M - 1) gr = M - 1;
                gld_lds16(Af + gr * lda + k0 + ((kc8 ^ r8) << 2),
                          AsH + buf * ASZ + ch * 512);
            }
        } else {
            const short* Ahi = (const short*)Aptr;
            int r16 = lane >> 2, g4 = lane & 3;
            int gs = (g4 ^ ((r16 >> 1) & 3)) * 8;   // granule swizzle (src side)
            #pragma unroll
            for (int cc = 0; cc < TM / 64; ++cc) {  // 2 chunks (TM=128) / 1 (TM=64)
                int ch = wave * (TM / 64) + cc;
                long gr = row0 + ch * 16 + r16;
                if (gr > M - 1) gr = M - 1;
                gld_lds16(Ahi + gr * lda + k0 + gs, AsH + ch * 512);
            }
        }
        {
            int r16 = lane >> 2, g4 = lane & 3;
            int gs = (g4 ^ ((r16 >> 1) & 3)) * 8;   // granule swizzle (src side)
            #pragma unroll
            for (int cc = 0; cc < 2; ++cc) {
                int ch = wave * 2 + cc;
                long gc = col0 + ch * 16 + r16;
                if (gc > Ntot - 1) gc = Ntot - 1;
                gld_lds16(Bhi + gc * ldbt + k0 + gs, BsH + buf * BSZ + ch * 512);
            }
        }
    };

    auto compute = [&](int buf) {
        bf16x8 aH[NI], bH[4];
        if constexpr (AF32) {
            #pragma unroll
            for (int i = 0; i < NI; ++i) {
                int row = wm * WR + i * 16 + l15;
                const float* fr = (const float*)(AsH + buf * ASZ) + row * 32;
                int x7 = row & 7;
                float4 f0 = *(const float4*)(fr + (((quad * 2)     ^ x7) << 2));
                float4 f1 = *(const float4*)(fr + (((quad * 2 + 1) ^ x7) << 2));
                aH[i] = (bf16x8){cvt_rn(f0.x), cvt_rn(f0.y), cvt_rn(f0.z), cvt_rn(f0.w),
                                 cvt_rn(f1.x), cvt_rn(f1.y), cvt_rn(f1.z), cvt_rn(f1.w)};
            }
        } else {
            #pragma unroll
            for (int i = 0; i < NI; ++i) {
                int row = wm * WR + i * 16 + l15;
                int off = row * 32 + ((quad ^ ((row >> 1) & 3)) * 8);
                aH[i] = *(const bf16x8*)&AsH[off];
            }
        }
        #pragma unroll
        for (int j = 0; j < 4; ++j) {
            int row = wn * 64 + j * 16 + l15;
            int off = buf * BSZ + row * 32 + ((quad ^ ((row >> 1) & 3)) * 8);
            bH[j] = *(const bf16x8*)&BsH[off];
        }
        #pragma unroll
        for (int i = 0; i < NI; ++i)
            #pragma unroll
            for (int j = 0; j < 4; ++j)
                acc[i][j] = __builtin_amdgcn_mfma_f32_16x16x32_bf16(aH[i], bH[j], acc[i][j], 0, 0, 0);
    };

    if constexpr (AF32) {
        stage(0, 0);
        int cur = 0;
        for (int kt = 0; kt < nkt; ++kt) {
            __syncthreads();
            if (kt + 1 < nkt) stage(cur ^ 1, (kt + 1) * GBK);
            compute(cur);
            cur ^= 1;
        }
    } else {
        for (int kt = 0; kt < nkt; ++kt) {
            stage(0, kt * GBK);
            __syncthreads();
            compute(0);
            __syncthreads();
        }
    }

    float gate = 0.f;
    if (mode == 3) gate = 1.f / (1.f + __expf(-skipGate[0]));
    _Float16* kvout = (_Float16*)Chi;   // mode 0 fp16 KV destination

    #pragma unroll
    for (int i = 0; i < NI; ++i) {
        #pragma unroll
        for (int r4 = 0; r4 < 4; ++r4) {
            long grow = row0 + wm * WR + i * 16 + quad * 4 + r4;
            if (grow >= M) continue;
            #pragma unroll
            for (int j = 0; j < 4; ++j) {
                long gcol = col0 + wn * 64 + j * 16 + l15;
                if (gcol >= Ntot) continue;
                float v = acc[i][j][r4];
                if (bias) v += bias[gcol];
                if (mode == 0) {
                    if (gcol < 128) Cf[grow * 128 + gcol] = v;
                    else kvout[grow * 512 + (gcol - 128)] = (_Float16)v;
                } else {
                    if (mode == 3) {
                        float pv = b2f(Phi[grow * 128 + gcol]);
                        v = gate * v + (1.f - gate) * pv;
                    }
                    v = fmaxf(v, 0.f);
                    Chi[grow * 128 + gcol] = cvt_rn(v);
                }
            }
        }
    }
}

// ============ build fused WbigT[640, F] bf16 plane + bias640 + WaT ============
// Column layout: [0,128) q | per (relation r, head h) contiguous 128-col
// block: k_rh (64) then v_rh (64). Block order: r0h0, r0h1, r1h0, r1h1.
// blockIdx.y in [640,768) writes the WaT transpose plane (fused).
__global__ __launch_bounds__(256) void build_wbigT_p(
    const float* __restrict__ Wq, const float* __restrict__ bq,
    const float* __restrict__ Wk, const float* __restrict__ bk,
    const float* __restrict__ Wv, const float* __restrict__ bv,
    const float* __restrict__ arel, const float* __restrict__ mrel,
    const float* __restrict__ Wa,
    short* __restrict__ WThi, short* __restrict__ WaThi,
    float* __restrict__ bias, int F)
{
    __shared__ float Trow[64];
    int c = blockIdx.y;
    int f = blockIdx.x * 256 + threadIdx.x;

    if (c >= 640) {                       // fused Wa transpose
        int cc = c - 640;                 // 0..127
        if (blockIdx.x == 0 && threadIdx.x < 128) {
            int ff = threadIdx.x;
            WaThi[cc * 128 + ff] = cvt_rn(Wa[(long)ff * 128 + cc]);
        }
        return;
    }

    float w = 0.f, b = 0.f;
    if (c < 128) {
        if (f < F) w = Wq[(long)f * 128 + c];
        b = bq[c];
    } else {
        int cc = c - 128;              // 0..511
        int r  = cc >> 8;              // relation
        int hb = cc & 255;             // within relation
        int h  = hb >> 7;              // head
        int kv = (hb >> 6) & 1;        // 0 = k, 1 = v
        int e  = hb & 63;              // element within head
        const float* Wsrc = kv ? Wv : Wk;
        const float* bsrc = kv ? bv : bk;
        const float* T    = kv ? mrel : arel;
        const float* Tr = T + (long)(r * 2 + h) * 4096 + e;
        if (threadIdx.x < 64) Trow[threadIdx.x] = Tr[(long)threadIdx.x * 64];
        __syncthreads();
        if (f < F) {
            const float* Wrow = Wsrc + (long)f * 128 + h * 64;
            float s = 0.f;
            #pragma unroll 4
            for (int d = 0; d < 64; ++d) s = fmaf(Wrow[d], Trow[d], s);
            w = s;
        }
        if (f == 0) {
            const float* brow = bsrc + h * 64;
            float sb = 0.f;
            for (int d = 0; d < 64; ++d) sb = fmaf(brow[d], Trow[d], sb);
            b = sb;
        }
    }
    if (f < F) WThi[(long)c * F + f] = cvt_rn(w);
    if (f == 0) bias[c] = b;
}

// ============ CSR build, both relations per launch (blockIdx.y = r) ============
__global__ void csr_count2(const int* __restrict__ e0p, const int* __restrict__ e1p,
                           int* __restrict__ counts, int E, int N)
{
    int e = blockIdx.x * 256 + threadIdx.x;
    int r = blockIdx.y;
    const int* dst = (r ? e1p : e0p) + E;
    if (e < E) atomicAdd(&counts[r * N + dst[e]], 1);
}

__global__ __launch_bounds__(1024) void csr_scan2(
    const int* __restrict__ counts,
    int* __restrict__ off0, int* __restrict__ off1,
    int* __restrict__ cursor, int N, int E)
{
    __shared__ int part[1024];
    int r = blockIdx.x;
    const int* cnt = counts + (long)r * N;
    int* offs = r ? off1 : off0;
    int* cur  = cursor + (long)r * N;
    int t = threadIdx.x;
    int chunk = (N + 1023) / 1024;
    int a = t * chunk, b = a + chunk; if (b > N) b = N;
    int s = 0;
    for (int i = a; i < b; ++i) s += cnt[i];
    part[t] = s;
    __syncthreads();
    for (int off = 1; off < 1024; off <<= 1) {
        int v = (t >= off) ? part[t - off] : 0;
        __syncthreads();
        if (t >= off) part[t] += v;
        __syncthreads();
    }
    int p = (t == 0) ? 0 : part[t - 1];
    for (int i = a; i < b; ++i) {
        offs[i] = p; cur[i] = p; p += cnt[i];
    }
    if (t == 1023) offs[N] = E;
}

__global__ void csr_fill2(const int* __restrict__ e0p, const int* __restrict__ e1p,
                          int* __restrict__ cursor,
                          int* __restrict__ ss0, int* __restrict__ ss1, int E, int N)
{
    int e = blockIdx.x * 256 + threadIdx.x;
    if (e >= E) return;
    int r = blockIdx.y;
    const int* ed = r ? e1p : e0p;
    int* ss = r ? ss1 : ss0;
    int pos = atomicAdd(&cursor[r * N + ed[E + e]], 1);
    ss[pos] = ed[e];
}

// ============ node attention: one wave per node, both heads (R9 form) ============
// fp16 KV gathers (512 B/edge both heads), 2 edge slots, xor-32 epilogue.
// R12: output bf16 hi plane only (RTN).
__global__ __launch_bounds__(256) void node_attn_kernel(
    const float* __restrict__ qf,          // [N][128] f32
    const _Float16* __restrict__ kvh,      // [N][512] fp16
    const int* __restrict__ off0, const int* __restrict__ ss0,
    const int* __restrict__ off1, const int* __restrict__ ss1,
    const float* __restrict__ prel,        // [2][2] (r,h)
    short* __restrict__ ohi, int N)
{
    int d = blockIdx.x * 4 + (threadIdx.x >> 6);
    if (d >= N) return;
    int lane = threadIdx.x & 63;
    int g = lane >> 5, h = (lane >> 4) & 1, l = lane & 15;

    float4 q4 = *(const float4*)(qf + (long)d * 128 + h * 64 + l * 4);

    int c0 = off0[d], b0 = off0[d + 1];
    int c1 = off1[d], b1 = off1[d + 1];
    const _Float16* kp0 = kvh + h * 128 + l * 4;
    const _Float16* vp0 = kp0 + 64;
    const _Float16* kp1 = kp0 + 256;
    const _Float16* vp1 = vp0 + 256;
    float pr0 = prel[h] * 0.125f;       // includes 1/sqrt(64)
    float pr1 = prel[2 + h] * 0.125f;

    const float4 fz = {0.f, 0.f, 0.f, 0.f};
    float4 num0 = fz, num1 = fz;
    float den0 = 0.f, den1 = 0.f;

    while (c0 < b0 || c1 < b1) {
        float4 k0 = fz, v0 = fz, k1 = fz, v1 = fz;
        bool a0 = (c0 < b0) && (c0 + g < b0);
        bool a1 = (c1 < b1) && (c1 + g < b1);
        if (a0) {
            long so = (long)ss0[c0 + g] * 512;
            halfx4 kh = *(const halfx4*)(kp0 + so);
            halfx4 vh = *(const halfx4*)(vp0 + so);
            k0.x = (float)kh[0]; k0.y = (float)kh[1];
            k0.z = (float)kh[2]; k0.w = (float)kh[3];
            v0.x = (float)vh[0]; v0.y = (float)vh[1];
            v0.z = (float)vh[2]; v0.w = (float)vh[3];
        }
        if (a1) {
            long so = (long)ss1[c1 + g] * 512;
            halfx4 kh = *(const halfx4*)(kp1 + so);
            halfx4 vh = *(const halfx4*)(vp1 + so);
            k1.x = (float)kh[0]; k1.y = (float)kh[1];
            k1.z = (float)kh[2]; k1.w = (float)kh[3];
            v1.x = (float)vh[0]; v1.y = (float)vh[1];
            v1.z = (float)vh[2]; v1.w = (float)vh[3];
        }
        if (c0 < b0) {
            float p = q4.x*k0.x + q4.y*k0.y + q4.z*k0.z + q4.w*k0.w;
            p += __shfl_xor(p, 1, 16);
            p += __shfl_xor(p, 2, 16);
            p += __shfl_xor(p, 4, 16);
            p += __shfl_xor(p, 8, 16);
            float w = a0 ? __expf(p * pr0) : 0.f;
            den0 += w;
            num0.x = fmaf(w, v0.x, num0.x);
            num0.y = fmaf(w, v0.y, num0.y);
            num0.z = fmaf(w, v0.z, num0.z);
            num0.w = fmaf(w, v0.w, num0.w);
            c0 += 2;
        }
        if (c1 < b1) {
            float p = q4.x*k1.x + q4.y*k1.y + q4.z*k1.z + q4.w*k1.w;
            p += __shfl_xor(p, 1, 16);
            p += __shfl_xor(p, 2, 16);
            p += __shfl_xor(p, 4, 16);
            p += __shfl_xor(p, 8, 16);
            float w = a1 ? __expf(p * pr1) : 0.f;
            den1 += w;
            num1.x = fmaf(w, v1.x, num1.x);
            num1.y = fmaf(w, v1.y, num1.y);
            num1.z = fmaf(w, v1.z, num1.z);
            num1.w = fmaf(w, v1.w, num1.w);
            c1 += 2;
        }
    }

    den0 += __shfl_xor(den0, 32, 64);
    den1 += __shfl_xor(den1, 32, 64);
    float inv0 = 1.f / (den0 + 1e-16f);
    float inv1 = 1.f / (den1 + 1e-16f);
    float4 accv;
    accv.x = num0.x * inv0 + num1.x * inv1;
    accv.y = num0.y * inv0 + num1.y * inv1;
    accv.z = num0.z * inv0 + num1.z * inv1;
    accv.w = num0.w * inv0 + num1.w * inv1;
    accv.x += __shfl_xor(accv.x, 32, 64);
    accv.y += __shfl_xor(accv.y, 32, 64);
    accv.z += __shfl_xor(accv.z, 32, 64);
    accv.w += __shfl_xor(accv.w, 32, 64);

    if (g == 0) {   // 32 lanes: both heads' outputs
        const float is2 = 0.70710678118654752f;
        float o0 = 0.5f * accv.x * (1.f + erff(accv.x * is2));
        float o1 = 0.5f * accv.y * (1.f + erff(accv.y * is2));
        float o2 = 0.5f * accv.z * (1.f + erff(accv.z * is2));
        float o3 = 0.5f * accv.w * (1.f + erff(accv.w * is2));
        long oo = (long)d * 128 + h * 64 + l * 4;
        *(shortx4*)(ohi + oo) = (shortx4){cvt_rn(o0), cvt_rn(o1), cvt_rn(o2), cvt_rn(o3)};
    }
}

// ============ f32 vector GEMM kept for tiny MLP ============
#define BM 64
#define BN 64
#define BK 16
__global__ __launch_bounds__(256) void gemm_bias_kernel(
    const float* __restrict__ A, int lda,
    const float* __restrict__ B, int ldb,
    const float* __restrict__ bias,
    float* __restrict__ C, int ldc,
    int M, int K, int epilogue)
{
    __shared__ float As[BK][BM + 4];
    __shared__ float Bs[BK][BN + 4];
    const int t = threadIdx.x;
    const int row0 = blockIdx.y * BM;
    const int col0 = blockIdx.x * BN;
    const int tm = (t >> 4) << 2;
    const int tn = (t & 15) << 2;
    float acc[4][4] = {};
    for (int k0 = 0; k0 < K; k0 += BK) {
        #pragma unroll
        for (int i = 0; i < 4; ++i) {
            int idx = t + i * 256;
            int m = idx >> 4, kk = idx & 15;
            int gm = row0 + m;
            As[kk][m] = (gm < M) ? A[(long)gm * lda + (k0 + kk)] : 0.f;
        }
        #pragma unroll
        for (int i = 0; i < 4; ++i) {
            int idx = t + i * 256;
            int kk = idx >> 6, n = idx & 63;
            Bs[kk][n] = B[(long)(k0 + kk) * ldb + (col0 + n)];
        }
        __syncthreads();
        #pragma unroll
        for (int kk = 0; kk < BK; ++kk) {
            float a[4], b[4];
            #pragma unroll
            for (int i = 0; i < 4; ++i) a[i] = As[kk][tm + i];
            #pragma unroll
            for (int j = 0; j < 4; ++j) b[j] = Bs[kk][tn + j];
            #pragma unroll
            for (int i = 0; i < 4; ++i)
                #pragma unroll
                for (int j = 0; j < 4; ++j)
                    acc[i][j] = fmaf(a[i], b[j], acc[i][j]);
        }
        __syncthreads();
    }
    #pragma unroll
    for (int i = 0; i < 4; ++i) {
        int gm = row0 + tm + i;
        if (gm >= M) continue;
        #pragma unroll
        for (int j = 0; j < 4; ++j) {
            int gn = col0 + tn + j;
            float v = acc[i][j];
            if (bias) v += bias[gn];
            if (epilogue >= 1) v = fmaxf(v, 0.f);
            C[(long)gm * ldc + gn] = v;
        }
    }
}

// ============ pooling (reads bf16 hi plane) ============
__device__ inline int lower_bound_i(const int* __restrict__ a, int n, int v)
{
    int lo = 0, hi = n;
    while (lo < hi) { int mid = (lo + hi) >> 1; if (a[mid] < v) lo = mid + 1; else hi = mid; }
    return lo;
}

__global__ void pool_kernel(const short* __restrict__ hhi,
                            const int* __restrict__ batch,
                            float* __restrict__ s, int N)
{
    int g = blockIdx.x, part = blockIdx.y, c = threadIdx.x;
    int start = lower_bound_i(batch, N, g);
    int end = lower_bound_i(batch, N, g + 1);
    int cnt = end - start, parts = gridDim.y;
    int chunk = (cnt + parts - 1) / parts;
    int a = start + part * chunk;
    int b = a + chunk; if (b > end) b = end;
    if (a >= b) return;
    float sum = 0.f;
    for (int n = a; n < b; ++n)
        sum += b2f(hhi[(long)n * HDIM + c]);
    atomicAdd(&s[g * HDIM + c], sum);
}

__global__ void pool_finalize(const float* __restrict__ s, const int* __restrict__ batch,
                              float* __restrict__ g_out, int N)
{
    int g = blockIdx.x, c = threadIdx.x;
    int start = lower_bound_i(batch, N, g);
    int end = lower_bound_i(batch, N, g + 1);
    float cnt = (float)((end - start) > 1 ? (end - start) : 1);
    g_out[g * HDIM + c] = s[g * HDIM + c] / cnt;
}

// ============ host ============
extern "C" void kernel_launch(void* const* d_in, const int* in_sizes, int n_in,
                              void* d_out, int out_size, void* d_ws, size_t ws_size,
                              hipStream_t stream)
{
    const float* x      = (const float*)d_in[0];
    const int*   e0     = (const int*)d_in[1];
    const int*   e1     = (const int*)d_in[2];
    const int*   batch  = (const int*)d_in[3];
    const float* W_k1   = (const float*)d_in[4];
    const float* W_q1   = (const float*)d_in[5];
    const float* W_v1   = (const float*)d_in[6];
    const float* a_rel1 = (const float*)d_in[7];
    const float* m_rel1 = (const float*)d_in[8];
    const float* W_a1   = (const float*)d_in[9];
    const float* W_k23  = (const float*)d_in[10];
    const float* W_q23  = (const float*)d_in[11];
    const float* W_v23  = (const float*)d_in[12];
    const float* a_rel23= (const float*)d_in[13];
    const float* m_rel23= (const float*)d_in[14];
    const float* W_a23  = (const float*)d_in[15];
    const float* W_m1   = (const float*)d_in[16];
    const float* W_m2   = (const float*)d_in[17];
    const float* b_k1   = (const float*)d_in[18];
    const float* b_q1   = (const float*)d_in[19];
    const float* b_v1   = (const float*)d_in[20];
    const float* b_a1   = (const float*)d_in[21];
    const float* b_k23  = (const float*)d_in[22];
    const float* b_q23  = (const float*)d_in[23];
    const float* b_v23  = (const float*)d_in[24];
    const float* b_a23  = (const float*)d_in[25];
    const float* skip23 = (const float*)d_in[26];
    const float* b_m1   = (const float*)d_in[27];
    const float* b_m2   = (const float*)d_in[28];
    const float* p_rel1 = (const float*)d_in[29];
    const float* p_rel23= (const float*)d_in[30];

    const int N = N_NODES_C;
    const int E = in_sizes[1] / 2;
    const int F = in_sizes[0] / N;            // 512
    const long NP = (long)N * HDIM;           // 6.4M plane elements

    // ---- workspace layout (R11 offsets kept; former lo slots unused) ----
    float* ws    = (float*)d_ws;
    float*    Qf32 = ws;                                // N*128 f32 (25.6 MB)
    _Float16* KVh  = (_Float16*)(Qf32 + (long)N * 128); // N*512 fp16 (51.2 MB)
    short* ACChi = (short*)(KVh + (long)N * 512);       // plane slots
    short* ACClo = ACChi + NP;                          // unused (kept layout)
    short* H1hi  = ACClo + NP;
    short* H1lo  = H1hi + NP;                           // unused
    short* H2hi  = H1lo + NP;
    short* H2lo  = H2hi + NP;                           // unused
    short* WThi  = H2lo + NP;                           // 640*512 max
    short* WTlo  = WThi + 640 * 512;                    // unused
    short* WaThi = WTlo + 640 * 512;                    // 128*128
    short* WaTlo = WaThi + 128 * 128;                   // unused
    float* B640  = (float*)(WaTlo + 128 * 128);         // 640
    float* S     = B640 + 640;
    float* GM    = S + N_GRAPHS_C * HDIM;
    float* M1    = GM + N_GRAPHS_C * HDIM;
    int*   off0  = (int*)(M1 + N_GRAPHS_C * HDIM);      // N+1
    int*   ss0   = off0 + (N + 1);                      // E
    int*   off1  = ss0 + E;                             // N+1
    int*   ss1   = off1 + (N + 1);                      // E
    int*   counts = (int*)Qf32;                         // 2N ints, alias
    int*   cursor = counts + 2 * N;                     // 2N
    size_t needed = (size_t)((char*)(ss1 + E) - (char*)d_ws);
    if (ws_size < needed) return;

    // ---- build CSR once, both relations per launch ----
    {
        int eb = (E + 255) / 256;
        hipMemsetAsync(counts, 0, (size_t)(2 * N) * sizeof(int), stream);
        dim3 cg(eb, 2);
        csr_count2<<<cg, 256, 0, stream>>>(e0, e1, counts, E, N);
        csr_scan2<<<2, 1024, 0, stream>>>(counts, off0, off1, cursor, N, E);
        csr_fill2<<<cg, 256, 0, stream>>>(e0, e1, cursor, ss0, ss1, E, N);
    }

    const int nrb   = (N + GBM - 1) / GBM;   // 391 row blocks (TM=128)
    const int nrb64 = (N + 63) / 64;         // 782 row blocks (TM=64)

    auto run_layer = [&](const void* Ain, int AF, int Fin,
                         const float* Wk, const float* bk,
                         const float* Wq, const float* bq,
                         const float* Wv, const float* bv,
                         const float* arel, const float* mrel, const float* prel,
                         const float* Wa, const float* ba,
                         const float* gate, const short* skipHi,
                         short* outHi) {
        dim3 bg((Fin + 255) / 256, 768);   // [640,768) = fused WaT transpose
        build_wbigT_p<<<bg, 256, 0, stream>>>(Wq, bq, Wk, bk, Wv, bv,
                                              arel, mrel, Wa,
                                              WThi, WaThi, B640, Fin);
        int qb = (640 / GBN) * nrb;        // 1D grid, XCD-swizzled in-kernel
        if (AF)
            gemm_planes<1, 128><<<qb, 256, 0, stream>>>(Ain, Fin, WThi, Fin,
                B640, Qf32, (short*)KVh, N, 640, Fin, 0, nullptr, nullptr);
        else
            gemm_planes<0, 128><<<qb, 256, 0, stream>>>(Ain, Fin, WThi, Fin,
                B640, Qf32, (short*)KVh, N, 640, Fin, 0, nullptr, nullptr);

        node_attn_kernel<<<(N + 3) / 4, 256, 0, stream>>>(
            Qf32, KVh, off0, ss0, off1, ss1, prel, ACChi, N);

        // out-GEMM: TM=64 variant, 782 blocks at 4 blocks/CU
        gemm_planes<0, 64><<<nrb64, 256, 0, stream>>>(ACChi, 128, WaThi, 128,
            ba, nullptr, outHi, N, 128, 128,
            gate ? 3 : 2, gate, skipHi);
    };

    // layer 1 (f32 x input, no skip) -> H1 plane
    run_layer(x, 1, F, W_k1, b_k1, W_q1, b_q1, W_v1, b_v1,
              a_rel1, m_rel1, p_rel1, W_a1, b_a1,
              nullptr, nullptr, H1hi);
    // layer 2 (H1 plane, gated skip from H1) -> H2 plane
    run_layer(H1hi, 0, HDIM, W_k23, b_k23, W_q23, b_q23, W_v23, b_v23,
              a_rel23, m_rel23, p_rel23, W_a23, b_a23,
              skip23, H1hi, H2hi);
    // layer 3 (H2 plane, gated skip from H2) -> H1 plane (reuse)
    run_layer(H2hi, 0, HDIM, W_k23 + 16384, b_k23 + 128, W_q23 + 16384, b_q23 + 128,
              W_v23 + 16384, b_v23 + 128, a_rel23 + 16384, m_rel23 + 16384,
              p_rel23 + 4, W_a23 + 16384, b_a23 + 128,
              skip23 + 1, H2hi, H1hi);

    // global mean pool (batch sorted)
    hipMemsetAsync(S, 0, (size_t)N_GRAPHS_C * HDIM * sizeof(float), stream);
    dim3 pg(N_GRAPHS_C, 8);
    pool_kernel<<<pg, HDIM, 0, stream>>>(H1hi, batch, S, N);
    pool_finalize<<<N_GRAPHS_C, HDIM, 0, stream>>>(S, batch, GM, N);

    // MLP
    {
        dim3 g1(128 / BN, 1);
        gemm_bias_kernel<<<g1, 256, 0, stream>>>(GM, 128, W_m1, 128, b_m1, M1, 128,
                                                 N_GRAPHS_C, 128, 1);
        dim3 g2(256 / BN, 1);
        gemm_bias_kernel<<<g2, 256, 0, stream>>>(M1, 128, W_m2, 256, b_m2,
                                                 (float*)d_out, 256, N_GRAPHS_C, 128, 0);
    }
}

// Round 13
// 805.340 us; speedup vs baseline: 1.2086x; 1.0059x over previous
//
#include <hip/hip_runtime.h>
#include <math.h>
#include <stdint.h>

#define N_NODES_C 50000
#define N_GRAPHS_C 64
#define HDIM 128

typedef short bf16x8 __attribute__((ext_vector_type(8)));
typedef short shortx4 __attribute__((ext_vector_type(4)));
typedef float floatx4 __attribute__((ext_vector_type(4)));
typedef _Float16 halfx4 __attribute__((ext_vector_type(4)));

// f32 -> bf16 round-to-nearest-even
__device__ __forceinline__ short cvt_rn(float x) {
    union { float f; unsigned u; } a; a.f = x;
    unsigned r = a.u + 0x7FFFu + ((a.u >> 16) & 1u);
    return (short)(r >> 16);
}

__device__ __forceinline__ float b2f(short s) {
    union { unsigned u; float f; } x; x.u = ((unsigned)(unsigned short)s) << 16;
    return x.f;
}

// async global->LDS copy, 16 B per lane, LDS dest = wave-uniform base + lane*16
__device__ __forceinline__ void gld_lds16(const void* gsrc, void* ldst) {
    __builtin_amdgcn_global_load_lds(
        (const __attribute__((address_space(1))) unsigned int*)gsrc,
        (__attribute__((address_space(3))) unsigned int*)ldst,
        16, 0, 0);
}

// ============ x f32 -> bf16 pre-convert (R13) ============
// Same RTN rounding the AF32 GEMM path applied in-kernel -> zero precision
// change, but pays the conversion ONCE (153 MB traffic) instead of per-GEMM
// f32 staging (2x bytes) + 32 cvt/wave/k-tile on the VALU.
__global__ __launch_bounds__(256) void xcvt_kernel(
    const float* __restrict__ x, short* __restrict__ xb, long nq)
{
    long i = (long)blockIdx.x * 256 + threadIdx.x;
    long stride = (long)gridDim.x * 256;
    for (; i < nq; i += stride) {
        float4 f = *(const float4*)(x + i * 4);
        *(shortx4*)(xb + i * 4) =
            (shortx4){cvt_rn(f.x), cvt_rn(f.y), cvt_rn(f.z), cvt_rn(f.w)};
    }
}

// ============ MFMA GEMM, single bf16 plane, bf16 A only (R13) ============
// DB=1 (K=512 QKV): double-buffer 2-phase, 32 KB LDS, (256,3) — prefetch pays
//   over 16 k-tiles (R1/R6 evidence), one __syncthreads per k-tile.
// DB=0 (K=128 paths): single-buffer (R5/R6 measured best for short K-loops).
//   TM=128 QKV 2/3: 16 KB, (256,3). TM=64 out-GEMM: 12 KB, (256,4), grid 782.
// bf16 granule XOR-swizzle both sides; XCD-bijective block swizzle (frozen).
// mode 0: cols [0,128) -> f32 Q (ld 128); cols [128,640) -> fp16 KV (ld 512)
// mode 2: Chi = bf16 relu(v + bias)            (ldc = 128)
// mode 3: Chi = bf16 relu(gate*v+bias + (1-gate)*prev_hi)
#define GBM 128
#define GBN 128
#define GBK 32

template<int DB, int TM>
__global__ __launch_bounds__(256, TM == 64 ? 4 : 3) void gemm_planes(
    const short* __restrict__ Ahi, int lda,
    const short* __restrict__ Bhi, int ldbt,
    const float* __restrict__ bias,
    float* __restrict__ Cf, short* __restrict__ Chi,
    int M, int Ntot, int K,
    int mode, const float* __restrict__ skipGate,
    const short* __restrict__ Phi)
{
    constexpr int ASZ = TM * GBK;                              // shorts / buffer
    constexpr int BSZ = GBN * GBK;
    constexpr int NB  = DB ? 2 : 1;                            // LDS buffers
    constexpr int NI  = TM / 32;                               // A fragments/wave
    constexpr int WR  = TM / 2;                                // rows per wm group
    __shared__ __align__(16) short AsH[NB * ASZ];
    __shared__ __align__(16) short BsH[NB * BSZ];

    const int t = threadIdx.x;
    const int lane = t & 63;
    const int wave = t >> 6;
    const int wm = wave & 1, wn = wave >> 1;
    const int quad = lane >> 4, l15 = lane & 15;

    // XCD-bijective chunked swizzle (valid for any nwg), column-fastest decode
    const int nwg = gridDim.x, bid0 = blockIdx.x;
    const int qq = nwg >> 3, rr = nwg & 7;
    const int xcd = bid0 & 7, idx = bid0 >> 3;
    const int swz = (xcd < rr ? xcd * (qq + 1)
                              : rr * (qq + 1) + (xcd - rr) * qq) + idx;
    const int ncb = (Ntot + GBN - 1) / GBN;
    const long row0 = (long)(swz / ncb) * TM;
    const long col0 = (long)(swz % ncb) * GBN;

    floatx4 acc[NI][4];
    #pragma unroll
    for (int i = 0; i < NI; ++i)
        #pragma unroll
        for (int j = 0; j < 4; ++j)
            acc[i][j] = (floatx4){0.f, 0.f, 0.f, 0.f};

    const int nkt = K / GBK;

    auto stage = [&](int buf, int k0) {
        int r16 = lane >> 2, g4 = lane & 3;
        int gs = (g4 ^ ((r16 >> 1) & 3)) * 8;       // granule swizzle (src side)
        #pragma unroll
        for (int cc = 0; cc < TM / 64; ++cc) {      // 2 chunks (TM=128) / 1 (TM=64)
            int ch = wave * (TM / 64) + cc;
            long gr = row0 + ch * 16 + r16;
            if (gr > M - 1) gr = M - 1;
            gld_lds16(Ahi + gr * lda + k0 + gs, AsH + buf * ASZ + ch * 512);
        }
        #pragma unroll
        for (int cc = 0; cc < 2; ++cc) {
            int ch = wave * 2 + cc;
            long gc = col0 + ch * 16 + r16;
            if (gc > Ntot - 1) gc = Ntot - 1;
            gld_lds16(Bhi + gc * ldbt + k0 + gs, BsH + buf * BSZ + ch * 512);
        }
    };

    auto compute = [&](int buf) {
        bf16x8 aH[NI], bH[4];
        #pragma unroll
        for (int i = 0; i < NI; ++i) {
            int row = wm * WR + i * 16 + l15;
            int off = buf * ASZ + row * 32 + ((quad ^ ((row >> 1) & 3)) * 8);
            aH[i] = *(const bf16x8*)&AsH[off];
        }
        #pragma unroll
        for (int j = 0; j < 4; ++j) {
            int row = wn * 64 + j * 16 + l15;
            int off = buf * BSZ + row * 32 + ((quad ^ ((row >> 1) & 3)) * 8);
            bH[j] = *(const bf16x8*)&BsH[off];
        }
        #pragma unroll
        for (int i = 0; i < NI; ++i)
            #pragma unroll
            for (int j = 0; j < 4; ++j)
                acc[i][j] = __builtin_amdgcn_mfma_f32_16x16x32_bf16(aH[i], bH[j], acc[i][j], 0, 0, 0);
    };

    if constexpr (DB) {
        stage(0, 0);
        int cur = 0;
        for (int kt = 0; kt < nkt; ++kt) {
            __syncthreads();   // own stage landed; all waves done with cur^1
            if (kt + 1 < nkt) stage(cur ^ 1, (kt + 1) * GBK);
            compute(cur);
            cur ^= 1;
        }
    } else {
        for (int kt = 0; kt < nkt; ++kt) {
            stage(0, kt * GBK);
            __syncthreads();
            compute(0);
            __syncthreads();
        }
    }

    float gate = 0.f;
    if (mode == 3) gate = 1.f / (1.f + __expf(-skipGate[0]));
    _Float16* kvout = (_Float16*)Chi;   // mode 0 fp16 KV destination

    #pragma unroll
    for (int i = 0; i < NI; ++i) {
        #pragma unroll
        for (int r4 = 0; r4 < 4; ++r4) {
            long grow = row0 + wm * WR + i * 16 + quad * 4 + r4;
            if (grow >= M) continue;
            #pragma unroll
            for (int j = 0; j < 4; ++j) {
                long gcol = col0 + wn * 64 + j * 16 + l15;
                if (gcol >= Ntot) continue;
                float v = acc[i][j][r4];
                if (bias) v += bias[gcol];
                if (mode == 0) {
                    if (gcol < 128) Cf[grow * 128 + gcol] = v;
                    else kvout[grow * 512 + (gcol - 128)] = (_Float16)v;
                } else {
                    if (mode == 3) {
                        float pv = b2f(Phi[grow * 128 + gcol]);
                        v = gate * v + (1.f - gate) * pv;
                    }
                    v = fmaxf(v, 0.f);
                    Chi[grow * 128 + gcol] = cvt_rn(v);
                }
            }
        }
    }
}

// ============ build fused WbigT[640, F] bf16 plane + bias640 + WaT ============
// Column layout: [0,128) q | per (relation r, head h) contiguous 128-col
// block: k_rh (64) then v_rh (64). Block order: r0h0, r0h1, r1h0, r1h1.
// blockIdx.y in [640,768) writes the WaT transpose plane (fused).
__global__ __launch_bounds__(256) void build_wbigT_p(
    const float* __restrict__ Wq, const float* __restrict__ bq,
    const float* __restrict__ Wk, const float* __restrict__ bk,
    const float* __restrict__ Wv, const float* __restrict__ bv,
    const float* __restrict__ arel, const float* __restrict__ mrel,
    const float* __restrict__ Wa,
    short* __restrict__ WThi, short* __restrict__ WaThi,
    float* __restrict__ bias, int F)
{
    __shared__ float Trow[64];
    int c = blockIdx.y;
    int f = blockIdx.x * 256 + threadIdx.x;

    if (c >= 640) {                       // fused Wa transpose
        int cc = c - 640;                 // 0..127
        if (blockIdx.x == 0 && threadIdx.x < 128) {
            int ff = threadIdx.x;
            WaThi[cc * 128 + ff] = cvt_rn(Wa[(long)ff * 128 + cc]);
        }
        return;
    }

    float w = 0.f, b = 0.f;
    if (c < 128) {
        if (f < F) w = Wq[(long)f * 128 + c];
        b = bq[c];
    } else {
        int cc = c - 128;              // 0..511
        int r  = cc >> 8;              // relation
        int hb = cc & 255;             // within relation
        int h  = hb >> 7;              // head
        int kv = (hb >> 6) & 1;        // 0 = k, 1 = v
        int e  = hb & 63;              // element within head
        const float* Wsrc = kv ? Wv : Wk;
        const float* bsrc = kv ? bv : bk;
        const float* T    = kv ? mrel : arel;
        const float* Tr = T + (long)(r * 2 + h) * 4096 + e;
        if (threadIdx.x < 64) Trow[threadIdx.x] = Tr[(long)threadIdx.x * 64];
        __syncthreads();
        if (f < F) {
            const float* Wrow = Wsrc + (long)f * 128 + h * 64;
            float s = 0.f;
            #pragma unroll 4
            for (int d = 0; d < 64; ++d) s = fmaf(Wrow[d], Trow[d], s);
            w = s;
        }
        if (f == 0) {
            const float* brow = bsrc + h * 64;
            float sb = 0.f;
            for (int d = 0; d < 64; ++d) sb = fmaf(brow[d], Trow[d], sb);
            b = sb;
        }
    }
    if (f < F) WThi[(long)c * F + f] = cvt_rn(w);
    if (f == 0) bias[c] = b;
}

// ============ CSR build, both relations per launch (blockIdx.y = r) ============
__global__ void csr_count2(const int* __restrict__ e0p, const int* __restrict__ e1p,
                           int* __restrict__ counts, int E, int N)
{
    int e = blockIdx.x * 256 + threadIdx.x;
    int r = blockIdx.y;
    const int* dst = (r ? e1p : e0p) + E;
    if (e < E) atomicAdd(&counts[r * N + dst[e]], 1);
}

__global__ __launch_bounds__(1024) void csr_scan2(
    const int* __restrict__ counts,
    int* __restrict__ off0, int* __restrict__ off1,
    int* __restrict__ cursor, int N, int E)
{
    __shared__ int part[1024];
    int r = blockIdx.x;
    const int* cnt = counts + (long)r * N;
    int* offs = r ? off1 : off0;
    int* cur  = cursor + (long)r * N;
    int t = threadIdx.x;
    int chunk = (N + 1023) / 1024;
    int a = t * chunk, b = a + chunk; if (b > N) b = N;
    int s = 0;
    for (int i = a; i < b; ++i) s += cnt[i];
    part[t] = s;
    __syncthreads();
    for (int off = 1; off < 1024; off <<= 1) {
        int v = (t >= off) ? part[t - off] : 0;
        __syncthreads();
        if (t >= off) part[t] += v;
        __syncthreads();
    }
    int p = (t == 0) ? 0 : part[t - 1];
    for (int i = a; i < b; ++i) {
        offs[i] = p; cur[i] = p; p += cnt[i];
    }
    if (t == 1023) offs[N] = E;
}

__global__ void csr_fill2(const int* __restrict__ e0p, const int* __restrict__ e1p,
                          int* __restrict__ cursor,
                          int* __restrict__ ss0, int* __restrict__ ss1, int E, int N)
{
    int e = blockIdx.x * 256 + threadIdx.x;
    if (e >= E) return;
    int r = blockIdx.y;
    const int* ed = r ? e1p : e0p;
    int* ss = r ? ss1 : ss0;
    int pos = atomicAdd(&cursor[r * N + ed[E + e]], 1);
    ss[pos] = ed[e];
}

// ============ node attention: one wave per node, both heads (R9 form) ============
// fp16 KV gathers (512 B/edge both heads), 2 edge slots, xor-32 epilogue.
// Output bf16 hi plane (RTN).
__global__ __launch_bounds__(256) void node_attn_kernel(
    const float* __restrict__ qf,          // [N][128] f32
    const _Float16* __restrict__ kvh,      // [N][512] fp16
    const int* __restrict__ off0, const int* __restrict__ ss0,
    const int* __restrict__ off1, const int* __restrict__ ss1,
    const float* __restrict__ prel,        // [2][2] (r,h)
    short* __restrict__ ohi, int N)
{
    int d = blockIdx.x * 4 + (threadIdx.x >> 6);
    if (d >= N) return;
    int lane = threadIdx.x & 63;
    int g = lane >> 5, h = (lane >> 4) & 1, l = lane & 15;

    float4 q4 = *(const float4*)(qf + (long)d * 128 + h * 64 + l * 4);

    int c0 = off0[d], b0 = off0[d + 1];
    int c1 = off1[d], b1 = off1[d + 1];
    const _Float16* kp0 = kvh + h * 128 + l * 4;
    const _Float16* vp0 = kp0 + 64;
    const _Float16* kp1 = kp0 + 256;
    const _Float16* vp1 = vp0 + 256;
    float pr0 = prel[h] * 0.125f;       // includes 1/sqrt(64)
    float pr1 = prel[2 + h] * 0.125f;

    const float4 fz = {0.f, 0.f, 0.f, 0.f};
    float4 num0 = fz, num1 = fz;
    float den0 = 0.f, den1 = 0.f;

    while (c0 < b0 || c1 < b1) {
        float4 k0 = fz, v0 = fz, k1 = fz, v1 = fz;
        bool a0 = (c0 < b0) && (c0 + g < b0);
        bool a1 = (c1 < b1) && (c1 + g < b1);
        if (a0) {
            long so = (long)ss0[c0 + g] * 512;
            halfx4 kh = *(const halfx4*)(kp0 + so);
            halfx4 vh = *(const halfx4*)(vp0 + so);
            k0.x = (float)kh[0]; k0.y = (float)kh[1];
            k0.z = (float)kh[2]; k0.w = (float)kh[3];
            v0.x = (float)vh[0]; v0.y = (float)vh[1];
            v0.z = (float)vh[2]; v0.w = (float)vh[3];
        }
        if (a1) {
            long so = (long)ss1[c1 + g] * 512;
            halfx4 kh = *(const halfx4*)(kp1 + so);
            halfx4 vh = *(const halfx4*)(vp1 + so);
            k1.x = (float)kh[0]; k1.y = (float)kh[1];
            k1.z = (float)kh[2]; k1.w = (float)kh[3];
            v1.x = (float)vh[0]; v1.y = (float)vh[1];
            v1.z = (float)vh[2]; v1.w = (float)vh[3];
        }
        if (c0 < b0) {
            float p = q4.x*k0.x + q4.y*k0.y + q4.z*k0.z + q4.w*k0.w;
            p += __shfl_xor(p, 1, 16);
            p += __shfl_xor(p, 2, 16);
            p += __shfl_xor(p, 4, 16);
            p += __shfl_xor(p, 8, 16);
            float w = a0 ? __expf(p * pr0) : 0.f;
            den0 += w;
            num0.x = fmaf(w, v0.x, num0.x);
            num0.y = fmaf(w, v0.y, num0.y);
            num0.z = fmaf(w, v0.z, num0.z);
            num0.w = fmaf(w, v0.w, num0.w);
            c0 += 2;
        }
        if (c1 < b1) {
            float p = q4.x*k1.x + q4.y*k1.y + q4.z*k1.z + q4.w*k1.w;
            p += __shfl_xor(p, 1, 16);
            p += __shfl_xor(p, 2, 16);
            p += __shfl_xor(p, 4, 16);
            p += __shfl_xor(p, 8, 16);
            float w = a1 ? __expf(p * pr1) : 0.f;
            den1 += w;
            num1.x = fmaf(w, v1.x, num1.x);
            num1.y = fmaf(w, v1.y, num1.y);
            num1.z = fmaf(w, v1.z, num1.z);
            num1.w = fmaf(w, v1.w, num1.w);
            c1 += 2;
        }
    }

    den0 += __shfl_xor(den0, 32, 64);
    den1 += __shfl_xor(den1, 32, 64);
    float inv0 = 1.f / (den0 + 1e-16f);
    float inv1 = 1.f / (den1 + 1e-16f);
    float4 accv;
    accv.x = num0.x * inv0 + num1.x * inv1;
    accv.y = num0.y * inv0 + num1.y * inv1;
    accv.z = num0.z * inv0 + num1.z * inv1;
    accv.w = num0.w * inv0 + num1.w * inv1;
    accv.x += __shfl_xor(accv.x, 32, 64);
    accv.y += __shfl_xor(accv.y, 32, 64);
    accv.z += __shfl_xor(accv.z, 32, 64);
    accv.w += __shfl_xor(accv.w, 32, 64);

    if (g == 0) {   // 32 lanes: both heads' outputs
        const float is2 = 0.70710678118654752f;
        float o0 = 0.5f * accv.x * (1.f + erff(accv.x * is2));
        float o1 = 0.5f * accv.y * (1.f + erff(accv.y * is2));
        float o2 = 0.5f * accv.z * (1.f + erff(accv.z * is2));
        float o3 = 0.5f * accv.w * (1.f + erff(accv.w * is2));
        long oo = (long)d * 128 + h * 64 + l * 4;
        *(shortx4*)(ohi + oo) = (shortx4){cvt_rn(o0), cvt_rn(o1), cvt_rn(o2), cvt_rn(o3)};
    }
}

// ============ f32 vector GEMM kept for tiny MLP ============
#define BM 64
#define BN 64
#define BK 16
__global__ __launch_bounds__(256) void gemm_bias_kernel(
    const float* __restrict__ A, int lda,
    const float* __restrict__ B, int ldb,
    const float* __restrict__ bias,
    float* __restrict__ C, int ldc,
    int M, int K, int epilogue)
{
    __shared__ float As[BK][BM + 4];
    __shared__ float Bs[BK][BN + 4];
    const int t = threadIdx.x;
    const int row0 = blockIdx.y * BM;
    const int col0 = blockIdx.x * BN;
    const int tm = (t >> 4) << 2;
    const int tn = (t & 15) << 2;
    float acc[4][4] = {};
    for (int k0 = 0; k0 < K; k0 += BK) {
        #pragma unroll
        for (int i = 0; i < 4; ++i) {
            int idx = t + i * 256;
            int m = idx >> 4, kk = idx & 15;
            int gm = row0 + m;
            As[kk][m] = (gm < M) ? A[(long)gm * lda + (k0 + kk)] : 0.f;
        }
        #pragma unroll
        for (int i = 0; i < 4; ++i) {
            int idx = t + i * 256;
            int kk = idx >> 6, n = idx & 63;
            Bs[kk][n] = B[(long)(k0 + kk) * ldb + (col0 + n)];
        }
        __syncthreads();
        #pragma unroll
        for (int kk = 0; kk < BK; ++kk) {
            float a[4], b[4];
            #pragma unroll
            for (int i = 0; i < 4; ++i) a[i] = As[kk][tm + i];
            #pragma unroll
            for (int j = 0; j < 4; ++j) b[j] = Bs[kk][tn + j];
            #pragma unroll
            for (int i = 0; i < 4; ++i)
                #pragma unroll
                for (int j = 0; j < 4; ++j)
                    acc[i][j] = fmaf(a[i], b[j], acc[i][j]);
        }
        __syncthreads();
    }
    #pragma unroll
    for (int i = 0; i < 4; ++i) {
        int gm = row0 + tm + i;
        if (gm >= M) continue;
        #pragma unroll
        for (int j = 0; j < 4; ++j) {
            int gn = col0 + tn + j;
            float v = acc[i][j];
            if (bias) v += bias[gn];
            if (epilogue >= 1) v = fmaxf(v, 0.f);
            C[(long)gm * ldc + gn] = v;
        }
    }
}

// ============ pooling (reads bf16 hi plane) ============
__device__ inline int lower_bound_i(const int* __restrict__ a, int n, int v)
{
    int lo = 0, hi = n;
    while (lo < hi) { int mid = (lo + hi) >> 1; if (a[mid] < v) lo = mid + 1; else hi = mid; }
    return lo;
}

__global__ void pool_kernel(const short* __restrict__ hhi,
                            const int* __restrict__ batch,
                            float* __restrict__ s, int N)
{
    int g = blockIdx.x, part = blockIdx.y, c = threadIdx.x;
    int start = lower_bound_i(batch, N, g);
    int end = lower_bound_i(batch, N, g + 1);
    int cnt = end - start, parts = gridDim.y;
    int chunk = (cnt + parts - 1) / parts;
    int a = start + part * chunk;
    int b = a + chunk; if (b > end) b = end;
    if (a >= b) return;
    float sum = 0.f;
    for (int n = a; n < b; ++n)
        sum += b2f(hhi[(long)n * HDIM + c]);
    atomicAdd(&s[g * HDIM + c], sum);
}

__global__ void pool_finalize(const float* __restrict__ s, const int* __restrict__ batch,
                              float* __restrict__ g_out, int N)
{
    int g = blockIdx.x, c = threadIdx.x;
    int start = lower_bound_i(batch, N, g);
    int end = lower_bound_i(batch, N, g + 1);
    float cnt = (float)((end - start) > 1 ? (end - start) : 1);
    g_out[g * HDIM + c] = s[g * HDIM + c] / cnt;
}

// ============ host ============
extern "C" void kernel_launch(void* const* d_in, const int* in_sizes, int n_in,
                              void* d_out, int out_size, void* d_ws, size_t ws_size,
                              hipStream_t stream)
{
    const float* x      = (const float*)d_in[0];
    const int*   e0     = (const int*)d_in[1];
    const int*   e1     = (const int*)d_in[2];
    const int*   batch  = (const int*)d_in[3];
    const float* W_k1   = (const float*)d_in[4];
    const float* W_q1   = (const float*)d_in[5];
    const float* W_v1   = (const float*)d_in[6];
    const float* a_rel1 = (const float*)d_in[7];
    const float* m_rel1 = (const float*)d_in[8];
    const float* W_a1   = (const float*)d_in[9];
    const float* W_k23  = (const float*)d_in[10];
    const float* W_q23  = (const float*)d_in[11];
    const float* W_v23  = (const float*)d_in[12];
    const float* a_rel23= (const float*)d_in[13];
    const float* m_rel23= (const float*)d_in[14];
    const float* W_a23  = (const float*)d_in[15];
    const float* W_m1   = (const float*)d_in[16];
    const float* W_m2   = (const float*)d_in[17];
    const float* b_k1   = (const float*)d_in[18];
    const float* b_q1   = (const float*)d_in[19];
    const float* b_v1   = (const float*)d_in[20];
    const float* b_a1   = (const float*)d_in[21];
    const float* b_k23  = (const float*)d_in[22];
    const float* b_q23  = (const float*)d_in[23];
    const float* b_v23  = (const float*)d_in[24];
    const float* b_a23  = (const float*)d_in[25];
    const float* skip23 = (const float*)d_in[26];
    const float* b_m1   = (const float*)d_in[27];
    const float* b_m2   = (const float*)d_in[28];
    const float* p_rel1 = (const float*)d_in[29];
    const float* p_rel23= (const float*)d_in[30];

    const int N = N_NODES_C;
    const int E = in_sizes[1] / 2;
    const int F = in_sizes[0] / N;            // 512
    const long NP = (long)N * HDIM;           // 6.4M plane elements

    // ---- workspace layout ----
    float* ws    = (float*)d_ws;
    float*    Qf32 = ws;                                // N*128 f32 (25.6 MB)
    _Float16* KVh  = (_Float16*)(Qf32 + (long)N * 128); // N*512 fp16 (51.2 MB)
    short* ACChi = (short*)(KVh + (long)N * 512);       // plane slots
    short* ACClo = ACChi + NP;                          // unused (kept layout)
    short* H1hi  = ACClo + NP;
    short* H1lo  = H1hi + NP;                           // unused
    short* H2hi  = H1lo + NP;
    short* H2lo  = H2hi + NP;                           // unused
    short* WThi  = H2lo + NP;                           // 640*512 max
    short* WTlo  = WThi + 640 * 512;                    // unused
    short* WaThi = WTlo + 640 * 512;                    // 128*128
    short* WaTlo = WaThi + 128 * 128;                   // unused
    float* B640  = (float*)(WaTlo + 128 * 128);         // 640
    float* S     = B640 + 640;
    float* GM    = S + N_GRAPHS_C * HDIM;
    float* M1    = GM + N_GRAPHS_C * HDIM;
    int*   off0  = (int*)(M1 + N_GRAPHS_C * HDIM);      // N+1
    int*   ss0   = off0 + (N + 1);                      // E
    int*   off1  = ss0 + E;                             // N+1
    int*   ss1   = off1 + (N + 1);                      // E
    short* Xbf   = (short*)(((uintptr_t)(ss1 + E) + 15) & ~(uintptr_t)15);  // N*F bf16
    int*   counts = (int*)Qf32;                         // 2N ints, alias
    int*   cursor = counts + 2 * N;                     // 2N
    size_t needed = (size_t)((char*)(Xbf + (long)N * F) - (char*)d_ws);
    if (ws_size < needed) return;

    // ---- build CSR once, both relations per launch; pre-convert x ----
    {
        int eb = (E + 255) / 256;
        hipMemsetAsync(counts, 0, (size_t)(2 * N) * sizeof(int), stream);
        dim3 cg(eb, 2);
        csr_count2<<<cg, 256, 0, stream>>>(e0, e1, counts, E, N);
        csr_scan2<<<2, 1024, 0, stream>>>(counts, off0, off1, cursor, N, E);
        csr_fill2<<<cg, 256, 0, stream>>>(e0, e1, cursor, ss0, ss1, E, N);
        xcvt_kernel<<<2048, 256, 0, stream>>>(x, Xbf, ((long)N * F) / 4);
    }

    const int nrb   = (N + GBM - 1) / GBM;   // 391 row blocks (TM=128)
    const int nrb64 = (N + 63) / 64;         // 782 row blocks (TM=64)

    auto run_layer = [&](const short* Ain, int DBsel, int Fin,
                         const float* Wk, const float* bk,
                         const float* Wq, const float* bq,
                         const float* Wv, const float* bv,
                         const float* arel, const float* mrel, const float* prel,
                         const float* Wa, const float* ba,
                         const float* gate, const short* skipHi,
                         short* outHi) {
        dim3 bg((Fin + 255) / 256, 768);   // [640,768) = fused WaT transpose
        build_wbigT_p<<<bg, 256, 0, stream>>>(Wq, bq, Wk, bk, Wv, bv,
                                              arel, mrel, Wa,
                                              WThi, WaThi, B640, Fin);
        int qb = (640 / GBN) * nrb;        // 1D grid, XCD-swizzled in-kernel
        if (DBsel)
            gemm_planes<1, 128><<<qb, 256, 0, stream>>>(Ain, Fin, WThi, Fin,
                B640, Qf32, (short*)KVh, N, 640, Fin, 0, nullptr, nullptr);
        else
            gemm_planes<0, 128><<<qb, 256, 0, stream>>>(Ain, Fin, WThi, Fin,
                B640, Qf32, (short*)KVh, N, 640, Fin, 0, nullptr, nullptr);

        node_attn_kernel<<<(N + 3) / 4, 256, 0, stream>>>(
            Qf32, KVh, off0, ss0, off1, ss1, prel, ACChi, N);

        // out-GEMM: TM=64 variant, 782 blocks at 4 blocks/CU
        gemm_planes<0, 64><<<nrb64, 256, 0, stream>>>(ACChi, 128, WaThi, 128,
            ba, nullptr, outHi, N, 128, 128,
            gate ? 3 : 2, gate, skipHi);
    };

    // layer 1 (bf16 x, K=512 -> dbuf) -> H1 plane
    run_layer(Xbf, 1, F, W_k1, b_k1, W_q1, b_q1, W_v1, b_v1,
              a_rel1, m_rel1, p_rel1, W_a1, b_a1,
              nullptr, nullptr, H1hi);
    // layer 2 (H1 plane, K=128 -> single-buffer, gated skip from H1) -> H2
    run_layer(H1hi, 0, HDIM, W_k23, b_k23, W_q23, b_q23, W_v23, b_v23,
              a_rel23, m_rel23, p_rel23, W_a23, b_a23,
              skip23, H1hi, H2hi);
    // layer 3 (H2 plane, gated skip from H2) -> H1 plane (reuse)
    run_layer(H2hi, 0, HDIM, W_k23 + 16384, b_k23 + 128, W_q23 + 16384, b_q23 + 128,
              W_v23 + 16384, b_v23 + 128, a_rel23 + 16384, m_rel23 + 16384,
              p_rel23 + 4, W_a23 + 16384, b_a23 + 128,
              skip23 + 1, H2hi, H1hi);

    // global mean pool (batch sorted)
    hipMemsetAsync(S, 0, (size_t)N_GRAPHS_C * HDIM * sizeof(float), stream);
    dim3 pg(N_GRAPHS_C, 8);
    pool_kernel<<<pg, HDIM, 0, stream>>>(H1hi, batch, S, N);
    pool_finalize<<<N_GRAPHS_C, HDIM, 0, stream>>>(S, batch, GM, N);

    // MLP
    {
        dim3 g1(128 / BN, 1);
        gemm_bias_kernel<<<g1, 256, 0, stream>>>(GM, 128, W_m1, 128, b_m1, M1, 128,
                                                 N_GRAPHS_C, 128, 1);
        dim3 g2(256 / BN, 1);
        gemm_bias_kernel<<<g2, 256, 0, stream>>>(M1, 128, W_m2, 256, b_m2,
                                                 (float*)d_out, 256, N_GRAPHS_C, 128, 0);
    }
}

// Round 14
// 717.242 us; speedup vs baseline: 1.3570x; 1.1228x over previous
//
#include <hip/hip_runtime.h>
#include <math.h>
#include <stdint.h>

#define N_NODES_C 50000
#define N_GRAPHS_C 64
#define HDIM 128

typedef short bf16x8 __attribute__((ext_vector_type(8)));
typedef short shortx4 __attribute__((ext_vector_type(4)));
typedef float floatx4 __attribute__((ext_vector_type(4)));
typedef _Float16 halfx4 __attribute__((ext_vector_type(4)));

// f32 -> bf16 round-to-nearest-even
__device__ __forceinline__ short cvt_rn(float x) {
    union { float f; unsigned u; } a; a.f = x;
    unsigned r = a.u + 0x7FFFu + ((a.u >> 16) & 1u);
    return (short)(r >> 16);
}

__device__ __forceinline__ float b2f(short s) {
    union { unsigned u; float f; } x; x.u = ((unsigned)(unsigned short)s) << 16;
    return x.f;
}

// async global->LDS copy, 16 B per lane, LDS dest = wave-uniform base + lane*16
__device__ __forceinline__ void gld_lds16(const void* gsrc, void* ldst) {
    __builtin_amdgcn_global_load_lds(
        (const __attribute__((address_space(1))) unsigned int*)gsrc,
        (__attribute__((address_space(3))) unsigned int*)ldst,
        16, 0, 0);
}

// ============ x f32 -> bf16 pre-convert (R13) ============
__global__ __launch_bounds__(256) void xcvt_kernel(
    const float* __restrict__ x, short* __restrict__ xb, long nq)
{
    long i = (long)blockIdx.x * 256 + threadIdx.x;
    long stride = (long)gridDim.x * 256;
    for (; i < nq; i += stride) {
        float4 f = *(const float4*)(x + i * 4);
        *(shortx4*)(xb + i * 4) =
            (shortx4){cvt_rn(f.x), cvt_rn(f.y), cvt_rn(f.z), cvt_rn(f.w)};
    }
}

// ============ MFMA GEMM, single bf16 plane (R13 config frozen) ============
// DB=1 (K=512 QKV): double-buffer 2-phase, 32 KB LDS, (256,3).
// DB=0 (K=128): single-buffer. TM=128 QKV 2/3: 16 KB. TM=64 out-GEMM: (256,4).
// bf16 granule XOR-swizzle both sides; XCD-bijective block swizzle.
// mode 0: cols [0,128) -> f32 Q (ld 128); cols [128,640) -> fp16 KV (ld 512)
// mode 2: Chi = bf16 relu(v + bias)            (ldc = 128)
// mode 3: Chi = bf16 relu(gate*v+bias + (1-gate)*prev_hi)
#define GBM 128
#define GBN 128
#define GBK 32

template<int DB, int TM>
__global__ __launch_bounds__(256, TM == 64 ? 4 : 3) void gemm_planes(
    const short* __restrict__ Ahi, int lda,
    const short* __restrict__ Bhi, int ldbt,
    const float* __restrict__ bias,
    float* __restrict__ Cf, short* __restrict__ Chi,
    int M, int Ntot, int K,
    int mode, const float* __restrict__ skipGate,
    const short* __restrict__ Phi)
{
    constexpr int ASZ = TM * GBK;                              // shorts / buffer
    constexpr int BSZ = GBN * GBK;
    constexpr int NB  = DB ? 2 : 1;                            // LDS buffers
    constexpr int NI  = TM / 32;                               // A fragments/wave
    constexpr int WR  = TM / 2;                                // rows per wm group
    __shared__ __align__(16) short AsH[NB * ASZ];
    __shared__ __align__(16) short BsH[NB * BSZ];

    const int t = threadIdx.x;
    const int lane = t & 63;
    const int wave = t >> 6;
    const int wm = wave & 1, wn = wave >> 1;
    const int quad = lane >> 4, l15 = lane & 15;

    // XCD-bijective chunked swizzle (valid for any nwg), column-fastest decode
    const int nwg = gridDim.x, bid0 = blockIdx.x;
    const int qq = nwg >> 3, rr = nwg & 7;
    const int xcd = bid0 & 7, idx = bid0 >> 3;
    const int swz = (xcd < rr ? xcd * (qq + 1)
                              : rr * (qq + 1) + (xcd - rr) * qq) + idx;
    const int ncb = (Ntot + GBN - 1) / GBN;
    const long row0 = (long)(swz / ncb) * TM;
    const long col0 = (long)(swz % ncb) * GBN;

    floatx4 acc[NI][4];
    #pragma unroll
    for (int i = 0; i < NI; ++i)
        #pragma unroll
        for (int j = 0; j < 4; ++j)
            acc[i][j] = (floatx4){0.f, 0.f, 0.f, 0.f};

    const int nkt = K / GBK;

    auto stage = [&](int buf, int k0) {
        int r16 = lane >> 2, g4 = lane & 3;
        int gs = (g4 ^ ((r16 >> 1) & 3)) * 8;       // granule swizzle (src side)
        #pragma unroll
        for (int cc = 0; cc < TM / 64; ++cc) {      // 2 chunks (TM=128) / 1 (TM=64)
            int ch = wave * (TM / 64) + cc;
            long gr = row0 + ch * 16 + r16;
            if (gr > M - 1) gr = M - 1;
            gld_lds16(Ahi + gr * lda + k0 + gs, AsH + buf * ASZ + ch * 512);
        }
        #pragma unroll
        for (int cc = 0; cc < 2; ++cc) {
            int ch = wave * 2 + cc;
            long gc = col0 + ch * 16 + r16;
            if (gc > Ntot - 1) gc = Ntot - 1;
            gld_lds16(Bhi + gc * ldbt + k0 + gs, BsH + buf * BSZ + ch * 512);
        }
    };

    auto compute = [&](int buf) {
        bf16x8 aH[NI], bH[4];
        #pragma unroll
        for (int i = 0; i < NI; ++i) {
            int row = wm * WR + i * 16 + l15;
            int off = buf * ASZ + row * 32 + ((quad ^ ((row >> 1) & 3)) * 8);
            aH[i] = *(const bf16x8*)&AsH[off];
        }
        #pragma unroll
        for (int j = 0; j < 4; ++j) {
            int row = wn * 64 + j * 16 + l15;
            int off = buf * BSZ + row * 32 + ((quad ^ ((row >> 1) & 3)) * 8);
            bH[j] = *(const bf16x8*)&BsH[off];
        }
        #pragma unroll
        for (int i = 0; i < NI; ++i)
            #pragma unroll
            for (int j = 0; j < 4; ++j)
                acc[i][j] = __builtin_amdgcn_mfma_f32_16x16x32_bf16(aH[i], bH[j], acc[i][j], 0, 0, 0);
    };

    if constexpr (DB) {
        stage(0, 0);
        int cur = 0;
        for (int kt = 0; kt < nkt; ++kt) {
            __syncthreads();   // own stage landed; all waves done with cur^1
            if (kt + 1 < nkt) stage(cur ^ 1, (kt + 1) * GBK);
            compute(cur);
            cur ^= 1;
        }
    } else {
        for (int kt = 0; kt < nkt; ++kt) {
            stage(0, kt * GBK);
            __syncthreads();
            compute(0);
            __syncthreads();
        }
    }

    float gate = 0.f;
    if (mode == 3) gate = 1.f / (1.f + __expf(-skipGate[0]));
    _Float16* kvout = (_Float16*)Chi;   // mode 0 fp16 KV destination

    #pragma unroll
    for (int i = 0; i < NI; ++i) {
        #pragma unroll
        for (int r4 = 0; r4 < 4; ++r4) {
            long grow = row0 + wm * WR + i * 16 + quad * 4 + r4;
            if (grow >= M) continue;
            #pragma unroll
            for (int j = 0; j < 4; ++j) {
                long gcol = col0 + wn * 64 + j * 16 + l15;
                if (gcol >= Ntot) continue;
                float v = acc[i][j][r4];
                if (bias) v += bias[gcol];
                if (mode == 0) {
                    if (gcol < 128) Cf[grow * 128 + gcol] = v;
                    else kvout[grow * 512 + (gcol - 128)] = (_Float16)v;
                } else {
                    if (mode == 3) {
                        float pv = b2f(Phi[grow * 128 + gcol]);
                        v = gate * v + (1.f - gate) * pv;
                    }
                    v = fmaxf(v, 0.f);
                    Chi[grow * 128 + gcol] = cvt_rn(v);
                }
            }
        }
    }
}

// ============ build fused WbigT[640, F] bf16 plane + bias640 + WaT ============
__global__ __launch_bounds__(256) void build_wbigT_p(
    const float* __restrict__ Wq, const float* __restrict__ bq,
    const float* __restrict__ Wk, const float* __restrict__ bk,
    const float* __restrict__ Wv, const float* __restrict__ bv,
    const float* __restrict__ arel, const float* __restrict__ mrel,
    const float* __restrict__ Wa,
    short* __restrict__ WThi, short* __restrict__ WaThi,
    float* __restrict__ bias, int F)
{
    __shared__ float Trow[64];
    int c = blockIdx.y;
    int f = blockIdx.x * 256 + threadIdx.x;

    if (c >= 640) {                       // fused Wa transpose
        int cc = c - 640;                 // 0..127
        if (blockIdx.x == 0 && threadIdx.x < 128) {
            int ff = threadIdx.x;
            WaThi[cc * 128 + ff] = cvt_rn(Wa[(long)ff * 128 + cc]);
        }
        return;
    }

    float w = 0.f, b = 0.f;
    if (c < 128) {
        if (f < F) w = Wq[(long)f * 128 + c];
        b = bq[c];
    } else {
        int cc = c - 128;              // 0..511
        int r  = cc >> 8;              // relation
        int hb = cc & 255;             // within relation
        int h  = hb >> 7;              // head
        int kv = (hb >> 6) & 1;        // 0 = k, 1 = v
        int e  = hb & 63;              // element within head
        const float* Wsrc = kv ? Wv : Wk;
        const float* bsrc = kv ? bv : bk;
        const float* T    = kv ? mrel : arel;
        const float* Tr = T + (long)(r * 2 + h) * 4096 + e;
        if (threadIdx.x < 64) Trow[threadIdx.x] = Tr[(long)threadIdx.x * 64];
        __syncthreads();
        if (f < F) {
            const float* Wrow = Wsrc + (long)f * 128 + h * 64;
            float s = 0.f;
            #pragma unroll 4
            for (int d = 0; d < 64; ++d) s = fmaf(Wrow[d], Trow[d], s);
            w = s;
        }
        if (f == 0) {
            const float* brow = bsrc + h * 64;
            float sb = 0.f;
            for (int d = 0; d < 64; ++d) sb = fmaf(brow[d], Trow[d], sb);
            b = sb;
        }
    }
    if (f < F) WThi[(long)c * F + f] = cvt_rn(w);
    if (f == 0) bias[c] = b;
}

// ============ CSR build (R14: 3-pass parallel scan replaces 2-block scan) ============
__global__ void csr_count2(const int* __restrict__ e0p, const int* __restrict__ e1p,
                           int* __restrict__ counts, int E, int N)
{
    int e = blockIdx.x * 256 + threadIdx.x;
    int r = blockIdx.y;
    const int* dst = (r ? e1p : e0p) + E;
    if (e < E) atomicAdd(&counts[r * N + dst[e]], 1);
}

// Pass A: per-block sums of 256 counts (coalesced)
__global__ __launch_bounds__(256) void scan_blksum(
    const int* __restrict__ counts, int* __restrict__ blksum, int N, int nb)
{
    int r = blockIdx.y, b = blockIdx.x, t = threadIdx.x;
    int i = b * 256 + t;
    __shared__ int sh[256];
    sh[t] = (i < N) ? counts[(long)r * N + i] : 0;
    __syncthreads();
    #pragma unroll
    for (int o = 128; o > 0; o >>= 1) {
        if (t < o) sh[t] += sh[t + o];
        __syncthreads();
    }
    if (t == 0) blksum[r * nb + b] = sh[0];
}

// Pass B: exclusive scan of nb block sums per relation (nb <= 1024)
__global__ __launch_bounds__(1024) void scan_blkoff(
    int* __restrict__ blksum, int nb)
{
    int r = blockIdx.x, t = threadIdx.x;
    __shared__ int sh[1024];
    int v = (t < nb) ? blksum[r * nb + t] : 0;
    sh[t] = v;
    __syncthreads();
    for (int o = 1; o < 1024; o <<= 1) {
        int u = (t >= o) ? sh[t - o] : 0;
        __syncthreads();
        sh[t] += u;
        __syncthreads();
    }
    if (t < nb) blksum[r * nb + t] = sh[t] - v;   // exclusive offset
}

// Pass C: in-block exclusive scan + block offset -> offs / cursor (coalesced)
__global__ __launch_bounds__(256) void scan_final(
    const int* __restrict__ counts, const int* __restrict__ blksum,
    int* __restrict__ off0, int* __restrict__ off1,
    int* __restrict__ cursor, int N, int nb, int E)
{
    int r = blockIdx.y, b = blockIdx.x, t = threadIdx.x;
    int i = b * 256 + t;
    int* offs = r ? off1 : off0;
    __shared__ int sh[256];
    int v = (i < N) ? counts[(long)r * N + i] : 0;
    sh[t] = v;
    __syncthreads();
    for (int o = 1; o < 256; o <<= 1) {
        int u = (t >= o) ? sh[t - o] : 0;
        __syncthreads();
        sh[t] += u;
        __syncthreads();
    }
    int excl = sh[t] - v + blksum[r * nb + b];
    if (i < N) { offs[i] = excl; cursor[(long)r * N + i] = excl; }
    if (i == 0 && b == 0) offs[N] = E;
}

__global__ void csr_fill2(const int* __restrict__ e0p, const int* __restrict__ e1p,
                          int* __restrict__ cursor,
                          int* __restrict__ ss0, int* __restrict__ ss1, int E, int N)
{
    int e = blockIdx.x * 256 + threadIdx.x;
    if (e >= E) return;
    int r = blockIdx.y;
    const int* ed = r ? e1p : e0p;
    int* ss = r ? ss1 : ss0;
    int pos = atomicAdd(&cursor[r * N + ed[E + e]], 1);
    ss[pos] = ed[e];
}

// ============ node attention: one wave per node, both heads (R9 form) ============
__global__ __launch_bounds__(256) void node_attn_kernel(
    const float* __restrict__ qf,          // [N][128] f32
    const _Float16* __restrict__ kvh,      // [N][512] fp16
    const int* __restrict__ off0, const int* __restrict__ ss0,
    const int* __restrict__ off1, const int* __restrict__ ss1,
    const float* __restrict__ prel,        // [2][2] (r,h)
    short* __restrict__ ohi, int N)
{
    int d = blockIdx.x * 4 + (threadIdx.x >> 6);
    if (d >= N) return;
    int lane = threadIdx.x & 63;
    int g = lane >> 5, h = (lane >> 4) & 1, l = lane & 15;

    float4 q4 = *(const float4*)(qf + (long)d * 128 + h * 64 + l * 4);

    int c0 = off0[d], b0 = off0[d + 1];
    int c1 = off1[d], b1 = off1[d + 1];
    const _Float16* kp0 = kvh + h * 128 + l * 4;
    const _Float16* vp0 = kp0 + 64;
    const _Float16* kp1 = kp0 + 256;
    const _Float16* vp1 = vp0 + 256;
    float pr0 = prel[h] * 0.125f;       // includes 1/sqrt(64)
    float pr1 = prel[2 + h] * 0.125f;

    const float4 fz = {0.f, 0.f, 0.f, 0.f};
    float4 num0 = fz, num1 = fz;
    float den0 = 0.f, den1 = 0.f;

    while (c0 < b0 || c1 < b1) {
        float4 k0 = fz, v0 = fz, k1 = fz, v1 = fz;
        bool a0 = (c0 < b0) && (c0 + g < b0);
        bool a1 = (c1 < b1) && (c1 + g < b1);
        if (a0) {
            long so = (long)ss0[c0 + g] * 512;
            halfx4 kh = *(const halfx4*)(kp0 + so);
            halfx4 vh = *(const halfx4*)(vp0 + so);
            k0.x = (float)kh[0]; k0.y = (float)kh[1];
            k0.z = (float)kh[2]; k0.w = (float)kh[3];
            v0.x = (float)vh[0]; v0.y = (float)vh[1];
            v0.z = (float)vh[2]; v0.w = (float)vh[3];
        }
        if (a1) {
            long so = (long)ss1[c1 + g] * 512;
            halfx4 kh = *(const halfx4*)(kp1 + so);
            halfx4 vh = *(const halfx4*)(vp1 + so);
            k1.x = (float)kh[0]; k1.y = (float)kh[1];
            k1.z = (float)kh[2]; k1.w = (float)kh[3];
            v1.x = (float)vh[0]; v1.y = (float)vh[1];
            v1.z = (float)vh[2]; v1.w = (float)vh[3];
        }
        if (c0 < b0) {
            float p = q4.x*k0.x + q4.y*k0.y + q4.z*k0.z + q4.w*k0.w;
            p += __shfl_xor(p, 1, 16);
            p += __shfl_xor(p, 2, 16);
            p += __shfl_xor(p, 4, 16);
            p += __shfl_xor(p, 8, 16);
            float w = a0 ? __expf(p * pr0) : 0.f;
            den0 += w;
            num0.x = fmaf(w, v0.x, num0.x);
            num0.y = fmaf(w, v0.y, num0.y);
            num0.z = fmaf(w, v0.z, num0.z);
            num0.w = fmaf(w, v0.w, num0.w);
            c0 += 2;
        }
        if (c1 < b1) {
            float p = q4.x*k1.x + q4.y*k1.y + q4.z*k1.z + q4.w*k1.w;
            p += __shfl_xor(p, 1, 16);
            p += __shfl_xor(p, 2, 16);
            p += __shfl_xor(p, 4, 16);
            p += __shfl_xor(p, 8, 16);
            float w = a1 ? __expf(p * pr1) : 0.f;
            den1 += w;
            num1.x = fmaf(w, v1.x, num1.x);
            num1.y = fmaf(w, v1.y, num1.y);
            num1.z = fmaf(w, v1.z, num1.z);
            num1.w = fmaf(w, v1.w, num1.w);
            c1 += 2;
        }
    }

    den0 += __shfl_xor(den0, 32, 64);
    den1 += __shfl_xor(den1, 32, 64);
    float inv0 = 1.f / (den0 + 1e-16f);
    float inv1 = 1.f / (den1 + 1e-16f);
    float4 accv;
    accv.x = num0.x * inv0 + num1.x * inv1;
    accv.y = num0.y * inv0 + num1.y * inv1;
    accv.z = num0.z * inv0 + num1.z * inv1;
    accv.w = num0.w * inv0 + num1.w * inv1;
    accv.x += __shfl_xor(accv.x, 32, 64);
    accv.y += __shfl_xor(accv.y, 32, 64);
    accv.z += __shfl_xor(accv.z, 32, 64);
    accv.w += __shfl_xor(accv.w, 32, 64);

    if (g == 0) {   // 32 lanes: both heads' outputs
        const float is2 = 0.70710678118654752f;
        float o0 = 0.5f * accv.x * (1.f + erff(accv.x * is2));
        float o1 = 0.5f * accv.y * (1.f + erff(accv.y * is2));
        float o2 = 0.5f * accv.z * (1.f + erff(accv.z * is2));
        float o3 = 0.5f * accv.w * (1.f + erff(accv.w * is2));
        long oo = (long)d * 128 + h * 64 + l * 4;
        *(shortx4*)(ohi + oo) = (shortx4){cvt_rn(o0), cvt_rn(o1), cvt_rn(o2), cvt_rn(o3)};
    }
}

// ============ f32 vector GEMM kept for tiny MLP ============
#define BM 64
#define BN 64
#define BK 16
__global__ __launch_bounds__(256) void gemm_bias_kernel(
    const float* __restrict__ A, int lda,
    const float* __restrict__ B, int ldb,
    const float* __restrict__ bias,
    float* __restrict__ C, int ldc,
    int M, int K, int epilogue)
{
    __shared__ float As[BK][BM + 4];
    __shared__ float Bs[BK][BN + 4];
    const int t = threadIdx.x;
    const int row0 = blockIdx.y * BM;
    const int col0 = blockIdx.x * BN;
    const int tm = (t >> 4) << 2;
    const int tn = (t & 15) << 2;
    float acc[4][4] = {};
    for (int k0 = 0; k0 < K; k0 += BK) {
        #pragma unroll
        for (int i = 0; i < 4; ++i) {
            int idx = t + i * 256;
            int m = idx >> 4, kk = idx & 15;
            int gm = row0 + m;
            As[kk][m] = (gm < M) ? A[(long)gm * lda + (k0 + kk)] : 0.f;
        }
        #pragma unroll
        for (int i = 0; i < 4; ++i) {
            int idx = t + i * 256;
            int kk = idx >> 6, n = idx & 63;
            Bs[kk][n] = B[(long)(k0 + kk) * ldb + (col0 + n)];
        }
        __syncthreads();
        #pragma unroll
        for (int kk = 0; kk < BK; ++kk) {
            float a[4], b[4];
            #pragma unroll
            for (int i = 0; i < 4; ++i) a[i] = As[kk][tm + i];
            #pragma unroll
            for (int j = 0; j < 4; ++j) b[j] = Bs[kk][tn + j];
            #pragma unroll
            for (int i = 0; i < 4; ++i)
                #pragma unroll
                for (int j = 0; j < 4; ++j)
                    acc[i][j] = fmaf(a[i], b[j], acc[i][j]);
        }
        __syncthreads();
    }
    #pragma unroll
    for (int i = 0; i < 4; ++i) {
        int gm = row0 + tm + i;
        if (gm >= M) continue;
        #pragma unroll
        for (int j = 0; j < 4; ++j) {
            int gn = col0 + tn + j;
            float v = acc[i][j];
            if (bias) v += bias[gn];
            if (epilogue >= 1) v = fmaxf(v, 0.f);
            C[(long)gm * ldc + gn] = v;
        }
    }
}

// ============ pooling (reads bf16 hi plane) ============
__device__ inline int lower_bound_i(const int* __restrict__ a, int n, int v)
{
    int lo = 0, hi = n;
    while (lo < hi) { int mid = (lo + hi) >> 1; if (a[mid] < v) lo = mid + 1; else hi = mid; }
    return lo;
}

__global__ void pool_kernel(const short* __restrict__ hhi,
                            const int* __restrict__ batch,
                            float* __restrict__ s, int N)
{
    int g = blockIdx.x, part = blockIdx.y, c = threadIdx.x;
    int start = lower_bound_i(batch, N, g);
    int end = lower_bound_i(batch, N, g + 1);
    int cnt = end - start, parts = gridDim.y;
    int chunk = (cnt + parts - 1) / parts;
    int a = start + part * chunk;
    int b = a + chunk; if (b > end) b = end;
    if (a >= b) return;
    float sum = 0.f;
    for (int n = a; n < b; ++n)
        sum += b2f(hhi[(long)n * HDIM + c]);
    atomicAdd(&s[g * HDIM + c], sum);
}

__global__ void pool_finalize(const float* __restrict__ s, const int* __restrict__ batch,
                              float* __restrict__ g_out, int N)
{
    int g = blockIdx.x, c = threadIdx.x;
    int start = lower_bound_i(batch, N, g);
    int end = lower_bound_i(batch, N, g + 1);
    float cnt = (float)((end - start) > 1 ? (end - start) : 1);
    g_out[g * HDIM + c] = s[g * HDIM + c] / cnt;
}

// ============ host ============
extern "C" void kernel_launch(void* const* d_in, const int* in_sizes, int n_in,
                              void* d_out, int out_size, void* d_ws, size_t ws_size,
                              hipStream_t stream)
{
    const float* x      = (const float*)d_in[0];
    const int*   e0     = (const int*)d_in[1];
    const int*   e1     = (const int*)d_in[2];
    const int*   batch  = (const int*)d_in[3];
    const float* W_k1   = (const float*)d_in[4];
    const float* W_q1   = (const float*)d_in[5];
    const float* W_v1   = (const float*)d_in[6];
    const float* a_rel1 = (const float*)d_in[7];
    const float* m_rel1 = (const float*)d_in[8];
    const float* W_a1   = (const float*)d_in[9];
    const float* W_k23  = (const float*)d_in[10];
    const float* W_q23  = (const float*)d_in[11];
    const float* W_v23  = (const float*)d_in[12];
    const float* a_rel23= (const float*)d_in[13];
    const float* m_rel23= (const float*)d_in[14];
    const float* W_a23  = (const float*)d_in[15];
    const float* W_m1   = (const float*)d_in[16];
    const float* W_m2   = (const float*)d_in[17];
    const float* b_k1   = (const float*)d_in[18];
    const float* b_q1   = (const float*)d_in[19];
    const float* b_v1   = (const float*)d_in[20];
    const float* b_a1   = (const float*)d_in[21];
    const float* b_k23  = (const float*)d_in[22];
    const float* b_q23  = (const float*)d_in[23];
    const float* b_v23  = (const float*)d_in[24];
    const float* b_a23  = (const float*)d_in[25];
    const float* skip23 = (const float*)d_in[26];
    const float* b_m1   = (const float*)d_in[27];
    const float* b_m2   = (const float*)d_in[28];
    const float* p_rel1 = (const float*)d_in[29];
    const float* p_rel23= (const float*)d_in[30];

    const int N = N_NODES_C;
    const int E = in_sizes[1] / 2;
    const int F = in_sizes[0] / N;            // 512
    const long NP = (long)N * HDIM;           // 6.4M plane elements

    // ---- workspace layout ----
    float* ws    = (float*)d_ws;
    float*    Qf32 = ws;                                // N*128 f32 (25.6 MB)
    _Float16* KVh  = (_Float16*)(Qf32 + (long)N * 128); // N*512 fp16 (51.2 MB)
    short* ACChi = (short*)(KVh + (long)N * 512);       // plane slots
    short* ACClo = ACChi + NP;                          // unused (kept layout)
    short* H1hi  = ACClo + NP;
    short* H1lo  = H1hi + NP;                           // unused
    short* H2hi  = H1lo + NP;
    short* H2lo  = H2hi + NP;                           // unused
    short* WThi  = H2lo + NP;                           // 640*512 max
    short* WTlo  = WThi + 640 * 512;                    // unused
    short* WaThi = WTlo + 640 * 512;                    // 128*128
    short* WaTlo = WaThi + 128 * 128;                   // unused
    float* B640  = (float*)(WaTlo + 128 * 128);         // 640
    float* S     = B640 + 640;
    float* GM    = S + N_GRAPHS_C * HDIM;
    float* M1    = GM + N_GRAPHS_C * HDIM;
    int*   off0  = (int*)(M1 + N_GRAPHS_C * HDIM);      // N+1
    int*   ss0   = off0 + (N + 1);                      // E
    int*   off1  = ss0 + E;                             // N+1
    int*   ss1   = off1 + (N + 1);                      // E
    short* Xbf   = (short*)(((uintptr_t)(ss1 + E) + 15) & ~(uintptr_t)15);  // N*F bf16
    int*   counts = (int*)Qf32;                         // 2N ints, alias
    int*   cursor = counts + 2 * N;                     // 2N
    int*   blksum = cursor + 2 * N;                     // 2*nb ints (alias in Qf32)
    size_t needed = (size_t)((char*)(Xbf + (long)N * F) - (char*)d_ws);
    if (ws_size < needed) return;

    const int nb = (N + 255) / 256;   // 196 scan blocks per relation

    // ---- build CSR once (3-pass parallel scan); pre-convert x ----
    {
        int eb = (E + 255) / 256;
        hipMemsetAsync(counts, 0, (size_t)(2 * N) * sizeof(int), stream);
        dim3 cg(eb, 2);
        csr_count2<<<cg, 256, 0, stream>>>(e0, e1, counts, E, N);
        dim3 sg(nb, 2);
        scan_blksum<<<sg, 256, 0, stream>>>(counts, blksum, N, nb);
        scan_blkoff<<<2, 1024, 0, stream>>>(blksum, nb);
        scan_final<<<sg, 256, 0, stream>>>(counts, blksum, off0, off1, cursor, N, nb, E);
        csr_fill2<<<cg, 256, 0, stream>>>(e0, e1, cursor, ss0, ss1, E, N);
        xcvt_kernel<<<2048, 256, 0, stream>>>(x, Xbf, ((long)N * F) / 4);
    }

    const int nrb   = (N + GBM - 1) / GBM;   // 391 row blocks (TM=128)
    const int nrb64 = (N + 63) / 64;         // 782 row blocks (TM=64)

    auto run_layer = [&](const short* Ain, int DBsel, int Fin,
                         const float* Wk, const float* bk,
                         const float* Wq, const float* bq,
                         const float* Wv, const float* bv,
                         const float* arel, const float* mrel, const float* prel,
                         const float* Wa, const float* ba,
                         const float* gate, const short* skipHi,
                         short* outHi) {
        dim3 bg((Fin + 255) / 256, 768);   // [640,768) = fused WaT transpose
        build_wbigT_p<<<bg, 256, 0, stream>>>(Wq, bq, Wk, bk, Wv, bv,
                                              arel, mrel, Wa,
                                              WThi, WaThi, B640, Fin);
        int qb = (640 / GBN) * nrb;        // 1D grid, XCD-swizzled in-kernel
        if (DBsel)
            gemm_planes<1, 128><<<qb, 256, 0, stream>>>(Ain, Fin, WThi, Fin,
                B640, Qf32, (short*)KVh, N, 640, Fin, 0, nullptr, nullptr);
        else
            gemm_planes<0, 128><<<qb, 256, 0, stream>>>(Ain, Fin, WThi, Fin,
                B640, Qf32, (short*)KVh, N, 640, Fin, 0, nullptr, nullptr);

        node_attn_kernel<<<(N + 3) / 4, 256, 0, stream>>>(
            Qf32, KVh, off0, ss0, off1, ss1, prel, ACChi, N);

        // out-GEMM: TM=64 variant, 782 blocks at 4 blocks/CU
        gemm_planes<0, 64><<<nrb64, 256, 0, stream>>>(ACChi, 128, WaThi, 128,
            ba, nullptr, outHi, N, 128, 128,
            gate ? 3 : 2, gate, skipHi);
    };

    // layer 1 (bf16 x, K=512 -> dbuf) -> H1 plane
    run_layer(Xbf, 1, F, W_k1, b_k1, W_q1, b_q1, W_v1, b_v1,
              a_rel1, m_rel1, p_rel1, W_a1, b_a1,
              nullptr, nullptr, H1hi);
    // layer 2 (H1 plane, K=128 -> single-buffer, gated skip from H1) -> H2
    run_layer(H1hi, 0, HDIM, W_k23, b_k23, W_q23, b_q23, W_v23, b_v23,
              a_rel23, m_rel23, p_rel23, W_a23, b_a23,
              skip23, H1hi, H2hi);
    // layer 3 (H2 plane, gated skip from H2) -> H1 plane (reuse)
    run_layer(H2hi, 0, HDIM, W_k23 + 16384, b_k23 + 128, W_q23 + 16384, b_q23 + 128,
              W_v23 + 16384, b_v23 + 128, a_rel23 + 16384, m_rel23 + 16384,
              p_rel23 + 4, W_a23 + 16384, b_a23 + 128,
              skip23 + 1, H2hi, H1hi);

    // global mean pool (batch sorted)
    hipMemsetAsync(S, 0, (size_t)N_GRAPHS_C * HDIM * sizeof(float), stream);
    dim3 pg(N_GRAPHS_C, 8);
    pool_kernel<<<pg, HDIM, 0, stream>>>(H1hi, batch, S, N);
    pool_finalize<<<N_GRAPHS_C, HDIM, 0, stream>>>(S, batch, GM, N);

    // MLP
    {
        dim3 g1(128 / BN, 1);
        gemm_bias_kernel<<<g1, 256, 0, stream>>>(GM, 128, W_m1, 128, b_m1, M1, 128,
                                                 N_GRAPHS_C, 128, 1);
        dim3 g2(256 / BN, 1);
        gemm_bias_kernel<<<g2, 256, 0, stream>>>(M1, 128, W_m2, 256, b_m2,
                                                 (float*)d_out, 256, N_GRAPHS_C, 128, 0);
    }
}

// Round 15
// 709.105 us; speedup vs baseline: 1.3726x; 1.0115x over previous
//
#include <hip/hip_runtime.h>
#include <math.h>
#include <stdint.h>

#define N_NODES_C 50000
#define N_GRAPHS_C 64
#define HDIM 128

typedef short bf16x8 __attribute__((ext_vector_type(8)));
typedef short shortx4 __attribute__((ext_vector_type(4)));
typedef float floatx4 __attribute__((ext_vector_type(4)));
typedef _Float16 halfx4 __attribute__((ext_vector_type(4)));

// f32 -> bf16 round-to-nearest-even
__device__ __forceinline__ short cvt_rn(float x) {
    union { float f; unsigned u; } a; a.f = x;
    unsigned r = a.u + 0x7FFFu + ((a.u >> 16) & 1u);
    return (short)(r >> 16);
}

__device__ __forceinline__ float b2f(short s) {
    union { unsigned u; float f; } x; x.u = ((unsigned)(unsigned short)s) << 16;
    return x.f;
}

// async global->LDS copy, 16 B per lane, LDS dest = wave-uniform base + lane*16
__device__ __forceinline__ void gld_lds16(const void* gsrc, void* ldst) {
    __builtin_amdgcn_global_load_lds(
        (const __attribute__((address_space(1))) unsigned int*)gsrc,
        (__attribute__((address_space(3))) unsigned int*)ldst,
        16, 0, 0);
}

// ============ x f32 -> bf16 pre-convert (R13) ============
__global__ __launch_bounds__(256) void xcvt_kernel(
    const float* __restrict__ x, short* __restrict__ xb, long nq)
{
    long i = (long)blockIdx.x * 256 + threadIdx.x;
    long stride = (long)gridDim.x * 256;
    for (; i < nq; i += stride) {
        float4 f = *(const float4*)(x + i * 4);
        *(shortx4*)(xb + i * 4) =
            (shortx4){cvt_rn(f.x), cvt_rn(f.y), cvt_rn(f.z), cvt_rn(f.w)};
    }
}

// ============ MFMA GEMM, single bf16 plane ============
// R15: (a) mode-0 Q output now fp16 (ld 128) — WRITE 77->64 MB/layer, attn
//      q-read halves; precision per R9 precedent (fp16 rel 2.4e-4 vanishes
//      under the 1/sqrt(780) pool attenuation).
//      (b) layer-1 QKV switches to TM=64 + DB=1: 24 KB LDS, (256,4) ->
//      4 blocks/CU (occupancy lever: paid at every step R5/R11/R12/R13),
//      grid 1955->3910, dbuf prefetch retained for the 16 k-tiles.
// DB=1: double-buffer 2-phase, one __syncthreads per k-tile.
// DB=0: single-buffer. TM=128 QKV 2/3 (16 KB, (256,3)); TM=64 out-GEMM (256,4).
// bf16 granule XOR-swizzle both sides; XCD-bijective block swizzle (frozen).
// mode 0: cols [0,128) -> fp16 Q (ld 128); cols [128,640) -> fp16 KV (ld 512)
// mode 2: Chi = bf16 relu(v + bias)            (ldc = 128)
// mode 3: Chi = bf16 relu(gate*v+bias + (1-gate)*prev_hi)
#define GBM 128
#define GBN 128
#define GBK 32

template<int DB, int TM>
__global__ __launch_bounds__(256, TM == 64 ? 4 : 3) void gemm_planes(
    const short* __restrict__ Ahi, int lda,
    const short* __restrict__ Bhi, int ldbt,
    const float* __restrict__ bias,
    _Float16* __restrict__ Qh, short* __restrict__ Chi,
    int M, int Ntot, int K,
    int mode, const float* __restrict__ skipGate,
    const short* __restrict__ Phi)
{
    constexpr int ASZ = TM * GBK;                              // shorts / buffer
    constexpr int BSZ = GBN * GBK;
    constexpr int NB  = DB ? 2 : 1;                            // LDS buffers
    constexpr int NI  = TM / 32;                               // A fragments/wave
    constexpr int WR  = TM / 2;                                // rows per wm group
    __shared__ __align__(16) short AsH[NB * ASZ];
    __shared__ __align__(16) short BsH[NB * BSZ];

    const int t = threadIdx.x;
    const int lane = t & 63;
    const int wave = t >> 6;
    const int wm = wave & 1, wn = wave >> 1;
    const int quad = lane >> 4, l15 = lane & 15;

    // XCD-bijective chunked swizzle (valid for any nwg), column-fastest decode
    const int nwg = gridDim.x, bid0 = blockIdx.x;
    const int qq = nwg >> 3, rr = nwg & 7;
    const int xcd = bid0 & 7, idx = bid0 >> 3;
    const int swz = (xcd < rr ? xcd * (qq + 1)
                              : rr * (qq + 1) + (xcd - rr) * qq) + idx;
    const int ncb = (Ntot + GBN - 1) / GBN;
    const long row0 = (long)(swz / ncb) * TM;
    const long col0 = (long)(swz % ncb) * GBN;

    floatx4 acc[NI][4];
    #pragma unroll
    for (int i = 0; i < NI; ++i)
        #pragma unroll
        for (int j = 0; j < 4; ++j)
            acc[i][j] = (floatx4){0.f, 0.f, 0.f, 0.f};

    const int nkt = K / GBK;

    auto stage = [&](int buf, int k0) {
        int r16 = lane >> 2, g4 = lane & 3;
        int gs = (g4 ^ ((r16 >> 1) & 3)) * 8;       // granule swizzle (src side)
        #pragma unroll
        for (int cc = 0; cc < TM / 64; ++cc) {      // 2 chunks (TM=128) / 1 (TM=64)
            int ch = wave * (TM / 64) + cc;
            long gr = row0 + ch * 16 + r16;
            if (gr > M - 1) gr = M - 1;
            gld_lds16(Ahi + gr * lda + k0 + gs, AsH + buf * ASZ + ch * 512);
        }
        #pragma unroll
        for (int cc = 0; cc < 2; ++cc) {
            int ch = wave * 2 + cc;
            long gc = col0 + ch * 16 + r16;
            if (gc > Ntot - 1) gc = Ntot - 1;
            gld_lds16(Bhi + gc * ldbt + k0 + gs, BsH + buf * BSZ + ch * 512);
        }
    };

    auto compute = [&](int buf) {
        bf16x8 aH[NI], bH[4];
        #pragma unroll
        for (int i = 0; i < NI; ++i) {
            int row = wm * WR + i * 16 + l15;
            int off = buf * ASZ + row * 32 + ((quad ^ ((row >> 1) & 3)) * 8);
            aH[i] = *(const bf16x8*)&AsH[off];
        }
        #pragma unroll
        for (int j = 0; j < 4; ++j) {
            int row = wn * 64 + j * 16 + l15;
            int off = buf * BSZ + row * 32 + ((quad ^ ((row >> 1) & 3)) * 8);
            bH[j] = *(const bf16x8*)&BsH[off];
        }
        #pragma unroll
        for (int i = 0; i < NI; ++i)
            #pragma unroll
            for (int j = 0; j < 4; ++j)
                acc[i][j] = __builtin_amdgcn_mfma_f32_16x16x32_bf16(aH[i], bH[j], acc[i][j], 0, 0, 0);
    };

    if constexpr (DB) {
        stage(0, 0);
        int cur = 0;
        for (int kt = 0; kt < nkt; ++kt) {
            __syncthreads();   // own stage landed; all waves done with cur^1
            if (kt + 1 < nkt) stage(cur ^ 1, (kt + 1) * GBK);
            compute(cur);
            cur ^= 1;
        }
    } else {
        for (int kt = 0; kt < nkt; ++kt) {
            stage(0, kt * GBK);
            __syncthreads();
            compute(0);
            __syncthreads();
        }
    }

    float gate = 0.f;
    if (mode == 3) gate = 1.f / (1.f + __expf(-skipGate[0]));
    _Float16* kvout = (_Float16*)Chi;   // mode 0 fp16 KV destination

    #pragma unroll
    for (int i = 0; i < NI; ++i) {
        #pragma unroll
        for (int r4 = 0; r4 < 4; ++r4) {
            long grow = row0 + wm * WR + i * 16 + quad * 4 + r4;
            if (grow >= M) continue;
            #pragma unroll
            for (int j = 0; j < 4; ++j) {
                long gcol = col0 + wn * 64 + j * 16 + l15;
                if (gcol >= Ntot) continue;
                float v = acc[i][j][r4];
                if (bias) v += bias[gcol];
                if (mode == 0) {
                    if (gcol < 128) Qh[grow * 128 + gcol] = (_Float16)v;
                    else kvout[grow * 512 + (gcol - 128)] = (_Float16)v;
                } else {
                    if (mode == 3) {
                        float pv = b2f(Phi[grow * 128 + gcol]);
                        v = gate * v + (1.f - gate) * pv;
                    }
                    v = fmaxf(v, 0.f);
                    Chi[grow * 128 + gcol] = cvt_rn(v);
                }
            }
        }
    }
}

// ============ build fused WbigT[640, F] bf16 plane + bias640 + WaT ============
__global__ __launch_bounds__(256) void build_wbigT_p(
    const float* __restrict__ Wq, const float* __restrict__ bq,
    const float* __restrict__ Wk, const float* __restrict__ bk,
    const float* __restrict__ Wv, const float* __restrict__ bv,
    const float* __restrict__ arel, const float* __restrict__ mrel,
    const float* __restrict__ Wa,
    short* __restrict__ WThi, short* __restrict__ WaThi,
    float* __restrict__ bias, int F)
{
    __shared__ float Trow[64];
    int c = blockIdx.y;
    int f = blockIdx.x * 256 + threadIdx.x;

    if (c >= 640) {                       // fused Wa transpose
        int cc = c - 640;                 // 0..127
        if (blockIdx.x == 0 && threadIdx.x < 128) {
            int ff = threadIdx.x;
            WaThi[cc * 128 + ff] = cvt_rn(Wa[(long)ff * 128 + cc]);
        }
        return;
    }

    float w = 0.f, b = 0.f;
    if (c < 128) {
        if (f < F) w = Wq[(long)f * 128 + c];
        b = bq[c];
    } else {
        int cc = c - 128;              // 0..511
        int r  = cc >> 8;              // relation
        int hb = cc & 255;             // within relation
        int h  = hb >> 7;              // head
        int kv = (hb >> 6) & 1;        // 0 = k, 1 = v
        int e  = hb & 63;              // element within head
        const float* Wsrc = kv ? Wv : Wk;
        const float* bsrc = kv ? bv : bk;
        const float* T    = kv ? mrel : arel;
        const float* Tr = T + (long)(r * 2 + h) * 4096 + e;
        if (threadIdx.x < 64) Trow[threadIdx.x] = Tr[(long)threadIdx.x * 64];
        __syncthreads();
        if (f < F) {
            const float* Wrow = Wsrc + (long)f * 128 + h * 64;
            float s = 0.f;
            #pragma unroll 4
            for (int d = 0; d < 64; ++d) s = fmaf(Wrow[d], Trow[d], s);
            w = s;
        }
        if (f == 0) {
            const float* brow = bsrc + h * 64;
            float sb = 0.f;
            for (int d = 0; d < 64; ++d) sb = fmaf(brow[d], Trow[d], sb);
            b = sb;
        }
    }
    if (f < F) WThi[(long)c * F + f] = cvt_rn(w);
    if (f == 0) bias[c] = b;
}

// ============ CSR build (3-pass parallel scan, R14) ============
__global__ void csr_count2(const int* __restrict__ e0p, const int* __restrict__ e1p,
                           int* __restrict__ counts, int E, int N)
{
    int e = blockIdx.x * 256 + threadIdx.x;
    int r = blockIdx.y;
    const int* dst = (r ? e1p : e0p) + E;
    if (e < E) atomicAdd(&counts[r * N + dst[e]], 1);
}

__global__ __launch_bounds__(256) void scan_blksum(
    const int* __restrict__ counts, int* __restrict__ blksum, int N, int nb)
{
    int r = blockIdx.y, b = blockIdx.x, t = threadIdx.x;
    int i = b * 256 + t;
    __shared__ int sh[256];
    sh[t] = (i < N) ? counts[(long)r * N + i] : 0;
    __syncthreads();
    #pragma unroll
    for (int o = 128; o > 0; o >>= 1) {
        if (t < o) sh[t] += sh[t + o];
        __syncthreads();
    }
    if (t == 0) blksum[r * nb + b] = sh[0];
}

__global__ __launch_bounds__(1024) void scan_blkoff(
    int* __restrict__ blksum, int nb)
{
    int r = blockIdx.x, t = threadIdx.x;
    __shared__ int sh[1024];
    int v = (t < nb) ? blksum[r * nb + t] : 0;
    sh[t] = v;
    __syncthreads();
    for (int o = 1; o < 1024; o <<= 1) {
        int u = (t >= o) ? sh[t - o] : 0;
        __syncthreads();
        sh[t] += u;
        __syncthreads();
    }
    if (t < nb) blksum[r * nb + t] = sh[t] - v;   // exclusive offset
}

__global__ __launch_bounds__(256) void scan_final(
    const int* __restrict__ counts, const int* __restrict__ blksum,
    int* __restrict__ off0, int* __restrict__ off1,
    int* __restrict__ cursor, int N, int nb, int E)
{
    int r = blockIdx.y, b = blockIdx.x, t = threadIdx.x;
    int i = b * 256 + t;
    int* offs = r ? off1 : off0;
    __shared__ int sh[256];
    int v = (i < N) ? counts[(long)r * N + i] : 0;
    sh[t] = v;
    __syncthreads();
    for (int o = 1; o < 256; o <<= 1) {
        int u = (t >= o) ? sh[t - o] : 0;
        __syncthreads();
        sh[t] += u;
        __syncthreads();
    }
    int excl = sh[t] - v + blksum[r * nb + b];
    if (i < N) { offs[i] = excl; cursor[(long)r * N + i] = excl; }
    if (i == 0 && b == 0) offs[N] = E;
}

__global__ void csr_fill2(const int* __restrict__ e0p, const int* __restrict__ e1p,
                          int* __restrict__ cursor,
                          int* __restrict__ ss0, int* __restrict__ ss1, int E, int N)
{
    int e = blockIdx.x * 256 + threadIdx.x;
    if (e >= E) return;
    int r = blockIdx.y;
    const int* ed = r ? e1p : e0p;
    int* ss = r ? ss1 : ss0;
    int pos = atomicAdd(&cursor[r * N + ed[E + e]], 1);
    ss[pos] = ed[e];
}

// ============ node attention: one wave per node, both heads (R9 form) ============
// R15: q read from fp16 (halves prologue q bytes).
__global__ __launch_bounds__(256) void node_attn_kernel(
    const _Float16* __restrict__ qh,       // [N][128] fp16
    const _Float16* __restrict__ kvh,      // [N][512] fp16
    const int* __restrict__ off0, const int* __restrict__ ss0,
    const int* __restrict__ off1, const int* __restrict__ ss1,
    const float* __restrict__ prel,        // [2][2] (r,h)
    short* __restrict__ ohi, int N)
{
    int d = blockIdx.x * 4 + (threadIdx.x >> 6);
    if (d >= N) return;
    int lane = threadIdx.x & 63;
    int g = lane >> 5, h = (lane >> 4) & 1, l = lane & 15;

    halfx4 qv = *(const halfx4*)(qh + (long)d * 128 + h * 64 + l * 4);
    float4 q4;
    q4.x = (float)qv[0]; q4.y = (float)qv[1];
    q4.z = (float)qv[2]; q4.w = (float)qv[3];

    int c0 = off0[d], b0 = off0[d + 1];
    int c1 = off1[d], b1 = off1[d + 1];
    const _Float16* kp0 = kvh + h * 128 + l * 4;
    const _Float16* vp0 = kp0 + 64;
    const _Float16* kp1 = kp0 + 256;
    const _Float16* vp1 = vp0 + 256;
    float pr0 = prel[h] * 0.125f;       // includes 1/sqrt(64)
    float pr1 = prel[2 + h] * 0.125f;

    const float4 fz = {0.f, 0.f, 0.f, 0.f};
    float4 num0 = fz, num1 = fz;
    float den0 = 0.f, den1 = 0.f;

    while (c0 < b0 || c1 < b1) {
        float4 k0 = fz, v0 = fz, k1 = fz, v1 = fz;
        bool a0 = (c0 < b0) && (c0 + g < b0);
        bool a1 = (c1 < b1) && (c1 + g < b1);
        if (a0) {
            long so = (long)ss0[c0 + g] * 512;
            halfx4 kh = *(const halfx4*)(kp0 + so);
            halfx4 vh = *(const halfx4*)(vp0 + so);
            k0.x = (float)kh[0]; k0.y = (float)kh[1];
            k0.z = (float)kh[2]; k0.w = (float)kh[3];
            v0.x = (float)vh[0]; v0.y = (float)vh[1];
            v0.z = (float)vh[2]; v0.w = (float)vh[3];
        }
        if (a1) {
            long so = (long)ss1[c1 + g] * 512;
            halfx4 kh = *(const halfx4*)(kp1 + so);
            halfx4 vh = *(const halfx4*)(vp1 + so);
            k1.x = (float)kh[0]; k1.y = (float)kh[1];
            k1.z = (float)kh[2]; k1.w = (float)kh[3];
            v1.x = (float)vh[0]; v1.y = (float)vh[1];
            v1.z = (float)vh[2]; v1.w = (float)vh[3];
        }
        if (c0 < b0) {
            float p = q4.x*k0.x + q4.y*k0.y + q4.z*k0.z + q4.w*k0.w;
            p += __shfl_xor(p, 1, 16);
            p += __shfl_xor(p, 2, 16);
            p += __shfl_xor(p, 4, 16);
            p += __shfl_xor(p, 8, 16);
            float w = a0 ? __expf(p * pr0) : 0.f;
            den0 += w;
            num0.x = fmaf(w, v0.x, num0.x);
            num0.y = fmaf(w, v0.y, num0.y);
            num0.z = fmaf(w, v0.z, num0.z);
            num0.w = fmaf(w, v0.w, num0.w);
            c0 += 2;
        }
        if (c1 < b1) {
            float p = q4.x*k1.x + q4.y*k1.y + q4.z*k1.z + q4.w*k1.w;
            p += __shfl_xor(p, 1, 16);
            p += __shfl_xor(p, 2, 16);
            p += __shfl_xor(p, 4, 16);
            p += __shfl_xor(p, 8, 16);
            float w = a1 ? __expf(p * pr1) : 0.f;
            den1 += w;
            num1.x = fmaf(w, v1.x, num1.x);
            num1.y = fmaf(w, v1.y, num1.y);
            num1.z = fmaf(w, v1.z, num1.z);
            num1.w = fmaf(w, v1.w, num1.w);
            c1 += 2;
        }
    }

    den0 += __shfl_xor(den0, 32, 64);
    den1 += __shfl_xor(den1, 32, 64);
    float inv0 = 1.f / (den0 + 1e-16f);
    float inv1 = 1.f / (den1 + 1e-16f);
    float4 accv;
    accv.x = num0.x * inv0 + num1.x * inv1;
    accv.y = num0.y * inv0 + num1.y * inv1;
    accv.z = num0.z * inv0 + num1.z * inv1;
    accv.w = num0.w * inv0 + num1.w * inv1;
    accv.x += __shfl_xor(accv.x, 32, 64);
    accv.y += __shfl_xor(accv.y, 32, 64);
    accv.z += __shfl_xor(accv.z, 32, 64);
    accv.w += __shfl_xor(accv.w, 32, 64);

    if (g == 0) {   // 32 lanes: both heads' outputs
        const float is2 = 0.70710678118654752f;
        float o0 = 0.5f * accv.x * (1.f + erff(accv.x * is2));
        float o1 = 0.5f * accv.y * (1.f + erff(accv.y * is2));
        float o2 = 0.5f * accv.z * (1.f + erff(accv.z * is2));
        float o3 = 0.5f * accv.w * (1.f + erff(accv.w * is2));
        long oo = (long)d * 128 + h * 64 + l * 4;
        *(shortx4*)(ohi + oo) = (shortx4){cvt_rn(o0), cvt_rn(o1), cvt_rn(o2), cvt_rn(o3)};
    }
}

// ============ f32 vector GEMM kept for tiny MLP ============
#define BM 64
#define BN 64
#define BK 16
__global__ __launch_bounds__(256) void gemm_bias_kernel(
    const float* __restrict__ A, int lda,
    const float* __restrict__ B, int ldb,
    const float* __restrict__ bias,
    float* __restrict__ C, int ldc,
    int M, int K, int epilogue)
{
    __shared__ float As[BK][BM + 4];
    __shared__ float Bs[BK][BN + 4];
    const int t = threadIdx.x;
    const int row0 = blockIdx.y * BM;
    const int col0 = blockIdx.x * BN;
    const int tm = (t >> 4) << 2;
    const int tn = (t & 15) << 2;
    float acc[4][4] = {};
    for (int k0 = 0; k0 < K; k0 += BK) {
        #pragma unroll
        for (int i = 0; i < 4; ++i) {
            int idx = t + i * 256;
            int m = idx >> 4, kk = idx & 15;
            int gm = row0 + m;
            As[kk][m] = (gm < M) ? A[(long)gm * lda + (k0 + kk)] : 0.f;
        }
        #pragma unroll
        for (int i = 0; i < 4; ++i) {
            int idx = t + i * 256;
            int kk = idx >> 6, n = idx & 63;
            Bs[kk][n] = B[(long)(k0 + kk) * ldb + (col0 + n)];
        }
        __syncthreads();
        #pragma unroll
        for (int kk = 0; kk < BK; ++kk) {
            float a[4], b[4];
            #pragma unroll
            for (int i = 0; i < 4; ++i) a[i] = As[kk][tm + i];
            #pragma unroll
            for (int j = 0; j < 4; ++j) b[j] = Bs[kk][tn + j];
            #pragma unroll
            for (int i = 0; i < 4; ++i)
                #pragma unroll
                for (int j = 0; j < 4; ++j)
                    acc[i][j] = fmaf(a[i], b[j], acc[i][j]);
        }
        __syncthreads();
    }
    #pragma unroll
    for (int i = 0; i < 4; ++i) {
        int gm = row0 + tm + i;
        if (gm >= M) continue;
        #pragma unroll
        for (int j = 0; j < 4; ++j) {
            int gn = col0 + tn + j;
            float v = acc[i][j];
            if (bias) v += bias[gn];
            if (epilogue >= 1) v = fmaxf(v, 0.f);
            C[(long)gm * ldc + gn] = v;
        }
    }
}

// ============ pooling (reads bf16 hi plane) ============
__device__ inline int lower_bound_i(const int* __restrict__ a, int n, int v)
{
    int lo = 0, hi = n;
    while (lo < hi) { int mid = (lo + hi) >> 1; if (a[mid] < v) lo = mid + 1; else hi = mid; }
    return lo;
}

__global__ void pool_kernel(const short* __restrict__ hhi,
                            const int* __restrict__ batch,
                            float* __restrict__ s, int N)
{
    int g = blockIdx.x, part = blockIdx.y, c = threadIdx.x;
    int start = lower_bound_i(batch, N, g);
    int end = lower_bound_i(batch, N, g + 1);
    int cnt = end - start, parts = gridDim.y;
    int chunk = (cnt + parts - 1) / parts;
    int a = start + part * chunk;
    int b = a + chunk; if (b > end) b = end;
    if (a >= b) return;
    float sum = 0.f;
    for (int n = a; n < b; ++n)
        sum += b2f(hhi[(long)n * HDIM + c]);
    atomicAdd(&s[g * HDIM + c], sum);
}

__global__ void pool_finalize(const float* __restrict__ s, const int* __restrict__ batch,
                              float* __restrict__ g_out, int N)
{
    int g = blockIdx.x, c = threadIdx.x;
    int start = lower_bound_i(batch, N, g);
    int end = lower_bound_i(batch, N, g + 1);
    float cnt = (float)((end - start) > 1 ? (end - start) : 1);
    g_out[g * HDIM + c] = s[g * HDIM + c] / cnt;
}

// ============ host ============
extern "C" void kernel_launch(void* const* d_in, const int* in_sizes, int n_in,
                              void* d_out, int out_size, void* d_ws, size_t ws_size,
                              hipStream_t stream)
{
    const float* x      = (const float*)d_in[0];
    const int*   e0     = (const int*)d_in[1];
    const int*   e1     = (const int*)d_in[2];
    const int*   batch  = (const int*)d_in[3];
    const float* W_k1   = (const float*)d_in[4];
    const float* W_q1   = (const float*)d_in[5];
    const float* W_v1   = (const float*)d_in[6];
    const float* a_rel1 = (const float*)d_in[7];
    const float* m_rel1 = (const float*)d_in[8];
    const float* W_a1   = (const float*)d_in[9];
    const float* W_k23  = (const float*)d_in[10];
    const float* W_q23  = (const float*)d_in[11];
    const float* W_v23  = (const float*)d_in[12];
    const float* a_rel23= (const float*)d_in[13];
    const float* m_rel23= (const float*)d_in[14];
    const float* W_a23  = (const float*)d_in[15];
    const float* W_m1   = (const float*)d_in[16];
    const float* W_m2   = (const float*)d_in[17];
    const float* b_k1   = (const float*)d_in[18];
    const float* b_q1   = (const float*)d_in[19];
    const float* b_v1   = (const float*)d_in[20];
    const float* b_a1   = (const float*)d_in[21];
    const float* b_k23  = (const float*)d_in[22];
    const float* b_q23  = (const float*)d_in[23];
    const float* b_v23  = (const float*)d_in[24];
    const float* b_a23  = (const float*)d_in[25];
    const float* skip23 = (const float*)d_in[26];
    const float* b_m1   = (const float*)d_in[27];
    const float* b_m2   = (const float*)d_in[28];
    const float* p_rel1 = (const float*)d_in[29];
    const float* p_rel23= (const float*)d_in[30];

    const int N = N_NODES_C;
    const int E = in_sizes[1] / 2;
    const int F = in_sizes[0] / N;            // 512
    const long NP = (long)N * HDIM;           // 6.4M plane elements

    // ---- workspace layout ----
    float* ws    = (float*)d_ws;
    _Float16* Qh  = (_Float16*)ws;                      // N*128 fp16 (12.8 MB, in old Qf32 slot)
    _Float16* KVh = (_Float16*)(ws + (long)N * 128);    // N*512 fp16 (51.2 MB)
    short* ACChi = (short*)(KVh + (long)N * 512);       // plane slots
    short* ACClo = ACChi + NP;                          // unused (kept layout)
    short* H1hi  = ACClo + NP;
    short* H1lo  = H1hi + NP;                           // unused
    short* H2hi  = H1lo + NP;
    short* H2lo  = H2hi + NP;                           // unused
    short* WThi  = H2lo + NP;                           // 640*512 max
    short* WTlo  = WThi + 640 * 512;                    // unused
    short* WaThi = WTlo + 640 * 512;                    // 128*128
    short* WaTlo = WaThi + 128 * 128;                   // unused
    float* B640  = (float*)(WaTlo + 128 * 128);         // 640
    float* S     = B640 + 640;
    float* GM    = S + N_GRAPHS_C * HDIM;
    float* M1    = GM + N_GRAPHS_C * HDIM;
    int*   off0  = (int*)(M1 + N_GRAPHS_C * HDIM);      // N+1
    int*   ss0   = off0 + (N + 1);                      // E
    int*   off1  = ss0 + E;                             // N+1
    int*   ss1   = off1 + (N + 1);                      // E
    short* Xbf   = (short*)(((uintptr_t)(ss1 + E) + 15) & ~(uintptr_t)15);  // N*F bf16
    int*   counts = (int*)ws;                           // 2N ints, alias (dead before Qh written)
    int*   cursor = counts + 2 * N;                     // 2N
    int*   blksum = cursor + 2 * N;                     // 2*nb ints (alias)
    size_t needed = (size_t)((char*)(Xbf + (long)N * F) - (char*)d_ws);
    if (ws_size < needed) return;

    const int nb = (N + 255) / 256;   // 196 scan blocks per relation

    // ---- build CSR once (3-pass parallel scan); pre-convert x ----
    {
        int eb = (E + 255) / 256;
        hipMemsetAsync(counts, 0, (size_t)(2 * N) * sizeof(int), stream);
        dim3 cg(eb, 2);
        csr_count2<<<cg, 256, 0, stream>>>(e0, e1, counts, E, N);
        dim3 sg(nb, 2);
        scan_blksum<<<sg, 256, 0, stream>>>(counts, blksum, N, nb);
        scan_blkoff<<<2, 1024, 0, stream>>>(blksum, nb);
        scan_final<<<sg, 256, 0, stream>>>(counts, blksum, off0, off1, cursor, N, nb, E);
        csr_fill2<<<cg, 256, 0, stream>>>(e0, e1, cursor, ss0, ss1, E, N);
        xcvt_kernel<<<2048, 256, 0, stream>>>(x, Xbf, ((long)N * F) / 4);
    }

    const int nrb   = (N + GBM - 1) / GBM;   // 391 row blocks (TM=128)
    const int nrb64 = (N + 63) / 64;         // 782 row blocks (TM=64)

    auto run_layer = [&](const short* Ain, int DBsel, int Fin,
                         const float* Wk, const float* bk,
                         const float* Wq, const float* bq,
                         const float* Wv, const float* bv,
                         const float* arel, const float* mrel, const float* prel,
                         const float* Wa, const float* ba,
                         const float* gate, const short* skipHi,
                         short* outHi) {
        dim3 bg((Fin + 255) / 256, 768);   // [640,768) = fused WaT transpose
        build_wbigT_p<<<bg, 256, 0, stream>>>(Wq, bq, Wk, bk, Wv, bv,
                                              arel, mrel, Wa,
                                              WThi, WaThi, B640, Fin);
        if (DBsel) {
            // layer-1 QKV: TM=64 dbuf, grid (640/128)*782 = 3910, 4 blocks/CU
            int qb = (640 / GBN) * nrb64;
            gemm_planes<1, 64><<<qb, 256, 0, stream>>>(Ain, Fin, WThi, Fin,
                B640, Qh, (short*)KVh, N, 640, Fin, 0, nullptr, nullptr);
        } else {
            int qb = (640 / GBN) * nrb;
            gemm_planes<0, 128><<<qb, 256, 0, stream>>>(Ain, Fin, WThi, Fin,
                B640, Qh, (short*)KVh, N, 640, Fin, 0, nullptr, nullptr);
        }

        node_attn_kernel<<<(N + 3) / 4, 256, 0, stream>>>(
            Qh, KVh, off0, ss0, off1, ss1, prel, ACChi, N);

        // out-GEMM: TM=64 variant, 782 blocks at 4 blocks/CU
        gemm_planes<0, 64><<<nrb64, 256, 0, stream>>>(ACChi, 128, WaThi, 128,
            ba, nullptr, outHi, N, 128, 128,
            gate ? 3 : 2, gate, skipHi);
    };

    // layer 1 (bf16 x, K=512 -> dbuf TM=64) -> H1 plane
    run_layer(Xbf, 1, F, W_k1, b_k1, W_q1, b_q1, W_v1, b_v1,
              a_rel1, m_rel1, p_rel1, W_a1, b_a1,
              nullptr, nullptr, H1hi);
    // layer 2 (H1 plane, K=128 -> single-buffer, gated skip from H1) -> H2
    run_layer(H1hi, 0, HDIM, W_k23, b_k23, W_q23, b_q23, W_v23, b_v23,
              a_rel23, m_rel23, p_rel23, W_a23, b_a23,
              skip23, H1hi, H2hi);
    // layer 3 (H2 plane, gated skip from H2) -> H1 plane (reuse)
    run_layer(H2hi, 0, HDIM, W_k23 + 16384, b_k23 + 128, W_q23 + 16384, b_q23 + 128,
              W_v23 + 16384, b_v23 + 128, a_rel23 + 16384, m_rel23 + 16384,
              p_rel23 + 4, W_a23 + 16384, b_a23 + 128,
              skip23 + 1, H2hi, H1hi);

    // global mean pool (batch sorted)
    hipMemsetAsync(S, 0, (size_t)N_GRAPHS_C * HDIM * sizeof(float), stream);
    dim3 pg(N_GRAPHS_C, 8);
    pool_kernel<<<pg, HDIM, 0, stream>>>(H1hi, batch, S, N);
    pool_finalize<<<N_GRAPHS_C, HDIM, 0, stream>>>(S, batch, GM, N);

    // MLP
    {
        dim3 g1(128 / BN, 1);
        gemm_bias_kernel<<<g1, 256, 0, stream>>>(GM, 128, W_m1, 128, b_m1, M1, 128,
                                                 N_GRAPHS_C, 128, 1);
        dim3 g2(256 / BN, 1);
        gemm_bias_kernel<<<g2, 256, 0, stream>>>(M1, 128, W_m2, 256, b_m2,
                                                 (float*)d_out, 256, N_GRAPHS_C, 128, 0);
    }
}